// Round 16
// baseline (365.396 us; speedup 1.0000x reference)
//
#include <hip/hip_runtime.h>
#include <hip/hip_bf16.h>
#include <cstdint>
#include <cstddef>

#define BB 4
#define SS 2048
#define DM 1024
#define INNER 2048
#define CHUNK 64
#define NCHK (SS / CHUNK)  // 32

typedef __attribute__((ext_vector_type(8))) __bf16 bf16x8;
typedef __attribute__((ext_vector_type(2))) float f32x2;
typedef __attribute__((ext_vector_type(4))) float f32x4;
typedef __attribute__((ext_vector_type(16))) float f32x16;
typedef __attribute__((ext_vector_type(8))) int i32x8;
typedef __attribute__((ext_vector_type(4))) int i32x4;
typedef __attribute__((ext_vector_type(8))) unsigned short ushort8;
typedef __attribute__((ext_vector_type(4))) unsigned short ushort4v;

#define GPTR(p) ((const __attribute__((address_space(1))) void*)(p))
#define LPTR(p) ((__attribute__((address_space(3))) void*)(p))
#define SB() __builtin_amdgcn_sched_barrier(0)

// Unit E8M0 scales (1.0) -> identical math to non-scaled fp8, 2x MFMA rate.
#define MXMFMA(b, a, c) \
  __builtin_amdgcn_mfma_scale_f32_32x32x64_f8f6f4((b), (a), (c), 0, 0, 0, 0x7f7f7f7f, 0, 0x7f7f7f7f)

// fp8 pre-scales (powers of 2; undone where consumed)
#define XN_SCALE 8.0f
#define WIN_SCALE 32.0f
#define PROJ_SCALE_INV (1.0f / 256.0f)
#define U_SCALE 128.0f
#define U_INV (1.0f / 128.0f)
#define W_SCALE 32.0f
#define ABC_SCALE_INV (1.0f / 4096.0f)
#define ABC8_SCALE 16.0f
#define ABC8_INV (1.0f / 16.0f)
#define Y_SCALE 128.0f
#define WO_SCALE 32.0f
#define WO_SCALE_INV (1.0f / 4096.0f)

__device__ inline float b2f(unsigned short h) {
  union { unsigned u; float f; } v; v.u = ((unsigned)h) << 16; return v.f;
}
__device__ inline unsigned short f2b(float f) {
  unsigned u = __float_as_uint(f);
  u += 0x7fff + ((u >> 16) & 1);   // round-to-nearest-even
  return (unsigned short)(u >> 16);
}
__device__ inline unsigned pack2(float lo, float hi) {
  return (unsigned)f2b(lo) | ((unsigned)f2b(hi) << 16);
}
__device__ inline unsigned pk_fp8x4(float a, float b, float c, float d) {
  unsigned w = 0;
  w = __builtin_amdgcn_cvt_pk_fp8_f32(a, b, (int)w, 0);
  w = __builtin_amdgcn_cvt_pk_fp8_f32(c, d, (int)w, 1);
  return w;
}
// HW fp8->f32: decode dword of 4 e4m3 bytes into f32x4 (2 pk-converts)
__device__ inline f32x4 up_fp8x4(unsigned w) {
  const f32x2 lo = __builtin_amdgcn_cvt_pk_f32_fp8((int)w, false);
  const f32x2 hi = __builtin_amdgcn_cvt_pk_f32_fp8((int)w, true);
  return (f32x4){lo[0], lo[1], hi[0], hi[1]};
}
__device__ inline float sigmoidf_(float x) { return 1.0f / (1.0f + __expf(-x)); }
__device__ inline float tanhf_(float x) { return 2.0f / (1.0f + __expf(-2.0f * x)) - 1.0f; }

// 32-byte MX fragment: two b128 reads at +0 / +256 (k-halves), regs linear in k
__device__ inline i32x8 ld32(const unsigned char* p) {
  i32x4 lo = *(const i32x4*)p;
  i32x4 hi = *(const i32x4*)(p + 256);
  i32x8 r;
  r[0] = lo[0]; r[1] = lo[1]; r[2] = lo[2]; r[3] = lo[3];
  r[4] = hi[0]; r[5] = hi[1]; r[6] = hi[2]; r[7] = hi[3];
  return r;
}

// ---------------------------------------------------------------------------
// Transpose + cast to fp8 e4m3 (scaled): src fp32 [R][C] -> dst fp8 [C][R]
// ---------------------------------------------------------------------------
__global__ void transpose_cast_fp8_kernel(const float* __restrict__ src,
                                          unsigned char* __restrict__ dst,
                                          int R, int C, float scale) {
  __shared__ float tile[32][33];
  const int c0 = blockIdx.x * 32, r0 = blockIdx.y * 32;
  const int tx = threadIdx.x, ty = threadIdx.y;  // (32,8)
  #pragma unroll
  for (int j = ty; j < 32; j += 8)
    tile[j][tx] = src[(size_t)(r0 + j) * C + c0 + tx];
  __syncthreads();
  #pragma unroll
  for (int j = ty; j < 32; j += 8) {
    const int w = __builtin_amdgcn_cvt_pk_fp8_f32(tile[tx][j] * scale, 0.f, 0, 0);
    dst[(size_t)(c0 + j) * R + r0 + tx] = (unsigned char)(w & 0xff);
  }
}

// ---------------------------------------------------------------------------
// LayerNorm: x fp32 [8192][1024] -> xn fp8 e4m3 (x XN_SCALE)
// ---------------------------------------------------------------------------
__global__ __launch_bounds__(256) void layernorm_kernel(
    const float* __restrict__ x, const float* __restrict__ gamma,
    const float* __restrict__ beta, unsigned char* __restrict__ out) {
  const int row = blockIdx.x;
  const int tid = threadIdx.x;
  const float4 v = *(const float4*)(x + (size_t)row * DM + tid * 4);
  float s = v.x + v.y + v.z + v.w;
  #pragma unroll
  for (int o = 32; o >= 1; o >>= 1) s += __shfl_down(s, o, 64);
  __shared__ float red[8];
  const int wid = tid >> 6, lane = tid & 63;
  if (lane == 0) red[wid] = s;
  __syncthreads();
  const float mu = (red[0] + red[1] + red[2] + red[3]) * (1.f / DM);
  const float d0 = v.x - mu, d1 = v.y - mu, d2 = v.z - mu, d3 = v.w - mu;
  float sq = d0 * d0 + d1 * d1 + d2 * d2 + d3 * d3;
  #pragma unroll
  for (int o = 32; o >= 1; o >>= 1) sq += __shfl_down(sq, o, 64);
  if (lane == 0) red[4 + wid] = sq;
  __syncthreads();
  const float var = (red[4] + red[5] + red[6] + red[7]) * (1.f / DM);
  const float rs = rsqrtf(var + 1e-5f);
  const int c0 = tid * 4;
  const float o0 = (d0 * rs * gamma[c0 + 0] + beta[c0 + 0]) * XN_SCALE;
  const float o1 = (d1 * rs * gamma[c0 + 1] + beta[c0 + 1]) * XN_SCALE;
  const float o2 = (d2 * rs * gamma[c0 + 2] + beta[c0 + 2]) * XN_SCALE;
  const float o3 = (d3 * rs * gamma[c0 + 3] + beta[c0 + 3]) * XN_SCALE;
  *(unsigned*)(out + (size_t)row * DM + c0) = pk_fp8x4(o0, o1, o2, o3);
}

// ---------------------------------------------------------------------------
// MX-fp8 256x256 GEMM, BK=128 (two 64-k sub-tiles per barrier pair).
// LDS: 2 bufs x (A 32KB + B 32KB) = 128 KB; each operand region = two 16 KB
// k-sub-regions with the R12-verified internal layout:
//   addr(r, s16) = (r>>4)*1024 + s*256 + (r&15)*16.
// vmcnt ledger (scaled 2x from proven BK=64): entry 8 outstanding;
// stageA128(t+1) -> 12; vmcnt(4) drains tile t exactly; stageB128(t+1) mid.
// 16 MFMAs/wave/tile between ONE barrier pair (halves barrier count per K).
// Swapped operands: lane holds C-row l&31, col clusters 4*(l>>5)+8g+{0..3}.
// OUTMODE 0: bf16 (v = acc*sinv + bias). OUTMODE 2: abc-fused fp8 stores.
// ---------------------------------------------------------------------------
template <int OUTMODE>
__global__ __launch_bounds__(512, 1) void gemm_mx(
    const unsigned char* __restrict__ A, const unsigned char* __restrict__ Bt,
    const float* __restrict__ bias, void* __restrict__ Cout,
    int M, int N, int K, int nbx, float sinv) {
  __shared__ __align__(16) unsigned char lds8[2 * 65536];  // 128 KB
  const int tid = threadIdx.x;
  const int nwg = gridDim.x;
  const int cpx = nwg >> 3;
  const int bid = blockIdx.x;
  const int swz = (bid & 7) * cpx + (bid >> 3);
  const int m0 = (swz / nbx) * 256, n0 = (swz % nbx) * 256;

  const int l = tid & 63, w = tid >> 6;
  const int wr = w >> 2, wc = w & 3;          // 2(M) x 4(N)
  const int NT = K >> 7;                      // K-tiles of 128

  const int lane_a = ((l >> 4) & 1) * 1024 + (l >> 5) * 512 + (l & 15) * 16;
  const int a_base = wr * 8192 + lane_a;              // + mf*2048 (+16384 ksub1)
  const int b_base = 32768 + wc * 4096 + lane_a;      // + nf*2048 (+16384 ksub1)

  f32x16 acc[4][2];
  {
    f32x16 z;
    #pragma unroll
    for (int e = 0; e < 16; e++) z[e] = 0.f;
    #pragma unroll
    for (int i = 0; i < 4; i++)
      #pragma unroll
      for (int j = 0; j < 2; j++) acc[i][j] = z;
  }

  const int ru = ((tid >> 6) << 4) | (tid & 15);
  const int su = (tid >> 4) & 3;
  const unsigned char* Af0 = A + (size_t)(m0 + ru) * K + su * 16;
  const unsigned char* Bf0 = Bt + (size_t)(n0 + ru) * K + su * 16;
  const size_t rs128 = (size_t)128 * K;

  auto stageA128 = [&](int kt) {
    int ktw = kt; if (ktw >= NT) ktw -= NT;
    const int k0 = ktw << 7;
    const int bo = (kt & 1) * 65536;
    __builtin_amdgcn_global_load_lds(GPTR(Af0 + k0), LPTR(&lds8[bo + tid * 16]), 16, 0, 0);
    __builtin_amdgcn_global_load_lds(GPTR(Af0 + rs128 + k0), LPTR(&lds8[bo + (tid + 512) * 16]), 16, 0, 0);
    __builtin_amdgcn_global_load_lds(GPTR(Af0 + k0 + 64), LPTR(&lds8[bo + 16384 + tid * 16]), 16, 0, 0);
    __builtin_amdgcn_global_load_lds(GPTR(Af0 + rs128 + k0 + 64), LPTR(&lds8[bo + 16384 + (tid + 512) * 16]), 16, 0, 0);
  };
  auto stageB128 = [&](int kt) {
    int ktw = kt; if (ktw >= NT) ktw -= NT;
    const int k0 = ktw << 7;
    const int bo = (kt & 1) * 65536 + 32768;
    __builtin_amdgcn_global_load_lds(GPTR(Bf0 + k0), LPTR(&lds8[bo + tid * 16]), 16, 0, 0);
    __builtin_amdgcn_global_load_lds(GPTR(Bf0 + rs128 + k0), LPTR(&lds8[bo + (tid + 512) * 16]), 16, 0, 0);
    __builtin_amdgcn_global_load_lds(GPTR(Bf0 + k0 + 64), LPTR(&lds8[bo + 16384 + tid * 16]), 16, 0, 0);
    __builtin_amdgcn_global_load_lds(GPTR(Bf0 + rs128 + k0 + 64), LPTR(&lds8[bo + 16384 + (tid + 512) * 16]), 16, 0, 0);
  };

  stageA128(0); stageB128(0);   // 8 outstanding

  for (int t = 0; t < NT; t++) {
    const int tbo = (t & 1) * 65536;
    i32x8 bf0, bf1, af0, af1, af2, af3;

    // stage A(t+1) [12 out]; vmcnt(4) -> tile t resident, A(t+1) in flight
    stageA128(t + 1);
    SB();
    asm volatile("s_waitcnt vmcnt(4)" ::: "memory");
    SB();
    __builtin_amdgcn_s_barrier();
    SB();
    // ---- k-sub 0 ----
    bf0 = ld32(&lds8[tbo + b_base]);
    bf1 = ld32(&lds8[tbo + b_base + 2048]);
    af0 = ld32(&lds8[tbo + a_base]);
    af1 = ld32(&lds8[tbo + a_base + 2048]);
    SB();
    __builtin_amdgcn_s_setprio(1);
    acc[0][0] = MXMFMA(bf0, af0, acc[0][0]);
    acc[0][1] = MXMFMA(bf1, af0, acc[0][1]);
    acc[1][0] = MXMFMA(bf0, af1, acc[1][0]);
    acc[1][1] = MXMFMA(bf1, af1, acc[1][1]);
    __builtin_amdgcn_s_setprio(0);
    SB();
    stageB128(t + 1);
    SB();
    af2 = ld32(&lds8[tbo + a_base + 2 * 2048]);
    af3 = ld32(&lds8[tbo + a_base + 3 * 2048]);
    SB();
    __builtin_amdgcn_s_setprio(1);
    acc[2][0] = MXMFMA(bf0, af2, acc[2][0]);
    acc[2][1] = MXMFMA(bf1, af2, acc[2][1]);
    acc[3][0] = MXMFMA(bf0, af3, acc[3][0]);
    acc[3][1] = MXMFMA(bf1, af3, acc[3][1]);
    __builtin_amdgcn_s_setprio(0);
    SB();
    // ---- k-sub 1 (+16384) ----
    bf0 = ld32(&lds8[tbo + b_base + 16384]);
    bf1 = ld32(&lds8[tbo + b_base + 16384 + 2048]);
    af0 = ld32(&lds8[tbo + a_base + 16384]);
    af1 = ld32(&lds8[tbo + a_base + 16384 + 2048]);
    SB();
    __builtin_amdgcn_s_setprio(1);
    acc[0][0] = MXMFMA(bf0, af0, acc[0][0]);
    acc[0][1] = MXMFMA(bf1, af0, acc[0][1]);
    acc[1][0] = MXMFMA(bf0, af1, acc[1][0]);
    acc[1][1] = MXMFMA(bf1, af1, acc[1][1]);
    __builtin_amdgcn_s_setprio(0);
    SB();
    af2 = ld32(&lds8[tbo + a_base + 16384 + 2 * 2048]);
    af3 = ld32(&lds8[tbo + a_base + 16384 + 3 * 2048]);
    SB();
    __builtin_amdgcn_s_setprio(1);
    acc[2][0] = MXMFMA(bf0, af2, acc[2][0]);
    acc[2][1] = MXMFMA(bf1, af2, acc[2][1]);
    acc[3][0] = MXMFMA(bf0, af3, acc[3][0]);
    acc[3][1] = MXMFMA(bf1, af3, acc[3][1]);
    __builtin_amdgcn_s_setprio(0);
    SB();
    __builtin_amdgcn_s_barrier();
    SB();
  }
  asm volatile("s_waitcnt vmcnt(0)" ::: "memory");

  // epilogue: lane holds C-row l&31, col clusters 4*(l>>5)+8g+{0..3}
  const int rowl = m0 + wr * 128 + (l & 31);
  const int colg = 4 * (l >> 5);
  const int seg = (OUTMODE == 2) ? (n0 >> 11) : 0;
  unsigned char* outseg8 = (unsigned char*)Cout +
      (OUTMODE == 2 ? (size_t)seg * M * 2048 : 0);
  #pragma unroll
  for (int mf = 0; mf < 4; mf++) {
    const int row = rowl + mf * 32;
    #pragma unroll
    for (int nf = 0; nf < 2; nf++) {
      const int nb = n0 + wc * 64 + nf * 32 + colg;
      #pragma unroll
      for (int g = 0; g < 4; g++) {
        const int col = nb + g * 8;
        const float4 bv = *(const float4*)(bias + col);
        float v0 = acc[mf][nf][g * 4 + 0] * sinv + bv.x;
        float v1 = acc[mf][nf][g * 4 + 1] * sinv + bv.y;
        float v2 = acc[mf][nf][g * 4 + 2] * sinv + bv.z;
        float v3 = acc[mf][nf][g * 4 + 3] * sinv + bv.w;
        if (OUTMODE == 2) {
          if (seg == 2) {
            v0 = tanhf_(v0); v1 = tanhf_(v1); v2 = tanhf_(v2); v3 = tanhf_(v3);
          } else {
            v0 = sigmoidf_(v0); v1 = sigmoidf_(v1); v2 = sigmoidf_(v2); v3 = sigmoidf_(v3);
          }
          *(unsigned*)(outseg8 + (size_t)row * 2048 + (col & 2047)) =
              pk_fp8x4(v0 * ABC8_SCALE, v1 * ABC8_SCALE,
                       v2 * ABC8_SCALE, v3 * ABC8_SCALE);
        } else {
          uint2 pk = {pack2(v0, v1), pack2(v2, v3)};
          *(uint2*)((unsigned short*)Cout + (size_t)row * N + col) = pk;
        }
      }
    }
  }
}

// ---------------------------------------------------------------------------
// MX-fp8 256x128 GEMM for Wo (R12-verified, BK=64). fp32 out + bias + resid.
// ---------------------------------------------------------------------------
__global__ __launch_bounds__(512, 1) void gemm_mx_wo(
    const unsigned char* __restrict__ A, const unsigned char* __restrict__ Bt,
    const float* __restrict__ bias, float* __restrict__ Cout,
    const float* __restrict__ resid, int M, int N, int K, int nbx) {
  __shared__ __align__(16) unsigned char lds8[2 * 24576];  // 48 KB
  const int tid = threadIdx.x;
  const int nwg = gridDim.x;
  const int cpx = nwg >> 3;
  const int bid = blockIdx.x;
  const int swz = (bid & 7) * cpx + (bid >> 3);
  const int m0 = (swz / nbx) * 256, n0 = (swz % nbx) * 128;

  const int l = tid & 63, w = tid >> 6;
  const int wr = w >> 1, wc = w & 1;          // 4(M) x 2(N)
  const int NT = K >> 6;

  const int lane_a = ((l >> 4) & 1) * 1024 + (l >> 5) * 512 + (l & 15) * 16;
  const int a_base = wr * 4096 + lane_a;              // + mf*2048
  const int b_base = 16384 + wc * 4096 + lane_a;      // + nf*2048

  f32x16 acc[2][2];
  {
    f32x16 z;
    #pragma unroll
    for (int e = 0; e < 16; e++) z[e] = 0.f;
    acc[0][0] = z; acc[0][1] = z; acc[1][0] = z; acc[1][1] = z;
  }

  const int ru = ((tid >> 6) << 4) | (tid & 15);
  const int su = (tid >> 4) & 3;
  const unsigned char* Af0 = A + (size_t)(m0 + ru) * K + su * 16;
  const unsigned char* Bf0 = Bt + (size_t)(n0 + ru) * K + su * 16;
  const size_t rs128 = (size_t)128 * K;

  auto stageA = [&](int kt) {
    int ktw = kt; if (ktw >= NT) ktw -= NT;
    const int k0 = ktw << 6;
    const int bo = (kt & 1) * 24576;
    __builtin_amdgcn_global_load_lds(GPTR(Af0 + k0), LPTR(&lds8[bo + tid * 16]), 16, 0, 0);
    __builtin_amdgcn_global_load_lds(GPTR(Af0 + rs128 + k0), LPTR(&lds8[bo + (tid + 512) * 16]), 16, 0, 0);
  };
  auto stageB = [&](int kt) {
    int ktw = kt; if (ktw >= NT) ktw -= NT;
    const int k0 = ktw << 6;
    const int bo = (kt & 1) * 24576 + 16384;
    __builtin_amdgcn_global_load_lds(GPTR(Bf0 + k0), LPTR(&lds8[bo + tid * 16]), 16, 0, 0);
  };

  stageA(0); stageB(0);   // 3 outstanding

  for (int t = 0; t < NT; t++) {
    const int tbo = (t & 1) * 24576;
    i32x8 bf0, bf1, af0, af1;

    stageA(t + 1);
    SB();
    asm volatile("s_waitcnt vmcnt(2)" ::: "memory");
    SB();
    __builtin_amdgcn_s_barrier();
    SB();
    bf0 = ld32(&lds8[tbo + b_base]);
    bf1 = ld32(&lds8[tbo + b_base + 2048]);
    af0 = ld32(&lds8[tbo + a_base]);
    SB();
    __builtin_amdgcn_s_setprio(1);
    acc[0][0] = MXMFMA(bf0, af0, acc[0][0]);
    acc[0][1] = MXMFMA(bf1, af0, acc[0][1]);
    __builtin_amdgcn_s_setprio(0);
    SB();
    stageB(t + 1);
    SB();
    af1 = ld32(&lds8[tbo + a_base + 2048]);
    SB();
    __builtin_amdgcn_s_setprio(1);
    acc[1][0] = MXMFMA(bf0, af1, acc[1][0]);
    acc[1][1] = MXMFMA(bf1, af1, acc[1][1]);
    __builtin_amdgcn_s_setprio(0);
    SB();
    __builtin_amdgcn_s_barrier();
    SB();
  }
  asm volatile("s_waitcnt vmcnt(0)" ::: "memory");

  const int rowl = m0 + wr * 64 + (l & 31);
  const int colg = 4 * (l >> 5);
  #pragma unroll
  for (int mf = 0; mf < 2; mf++) {
    const int row = rowl + mf * 32;
    #pragma unroll
    for (int nf = 0; nf < 2; nf++) {
      const int nb = n0 + wc * 64 + nf * 32 + colg;
      #pragma unroll
      for (int g = 0; g < 4; g++) {
        const int col = nb + g * 8;
        const float4 bv = *(const float4*)(bias + col);
        const size_t idx = (size_t)row * N + col;
        const float4 rv = *(const float4*)(resid + idx);
        float4 ov;
        ov.x = acc[mf][nf][g * 4 + 0] * WO_SCALE_INV + bv.x + rv.x;
        ov.y = acc[mf][nf][g * 4 + 1] * WO_SCALE_INV + bv.y + rv.y;
        ov.z = acc[mf][nf][g * 4 + 2] * WO_SCALE_INV + bv.z + rv.z;
        ov.w = acc[mf][nf][g * 4 + 3] * WO_SCALE_INV + bv.w + rv.w;
        *(float4*)(Cout + idx) = ov;
      }
    }
  }
}

// ---------------------------------------------------------------------------
// Causal depthwise conv (K=3) + SiLU + gate. proj bf16 in, u fp8 (x128) out.
// ---------------------------------------------------------------------------
__global__ __launch_bounds__(256) void conv_gate_kernel(
    const unsigned short* __restrict__ proj, const float* __restrict__ conv_w,
    const float* __restrict__ conv_b, unsigned char* __restrict__ u8) {
  const size_t idx = ((size_t)blockIdx.x * 256 + threadIdx.x) * 8;
  const int d = (int)(idx & (INNER - 1));
  const size_t bt = idx >> 11;
  const int t = (int)(bt & (SS - 1));
  const size_t rowbase = bt * (2 * INNER);
  const ushort8 zero = {0, 0, 0, 0, 0, 0, 0, 0};
  ushort8 p0 = *(const ushort8*)(proj + rowbase + d);
  ushort8 p1 = zero, p2 = zero;
  if (t >= 1) p1 = *(const ushort8*)(proj + rowbase - 2 * INNER + d);
  if (t >= 2) p2 = *(const ushort8*)(proj + rowbase - 4 * INNER + d);
  ushort8 g = *(const ushort8*)(proj + rowbase + INNER + d);
  float us[8];
  #pragma unroll
  for (int j = 0; j < 8; j++) {
    const int dj = d + j;
    float sv = conv_b[dj] + conv_w[dj * 3] * b2f(p2[j]) +
               conv_w[dj * 3 + 1] * b2f(p1[j]) + conv_w[dj * 3 + 2] * b2f(p0[j]);
    us[j] = sv * sigmoidf_(sv) * sigmoidf_(b2f(g[j]));
  }
  uint2 pk;
  pk.x = pk_fp8x4(us[0] * U_SCALE, us[1] * U_SCALE, us[2] * U_SCALE, us[3] * U_SCALE);
  pk.y = pk_fp8x4(us[4] * U_SCALE, us[5] * U_SCALE, us[6] * U_SCALE, us[7] * U_SCALE);
  *(uint2*)(u8 + idx) = pk;
}

// ---------------------------------------------------------------------------
// Chunked parallel scan, 3 phases. a,b,c fp8 (x16); u fp8 (x128).
// HW cvt_pk_f32_fp8 decode (2 instrs per 4 elems).
// ---------------------------------------------------------------------------
__global__ __launch_bounds__(256) void scan_phase1(
    const unsigned char* __restrict__ a8, const unsigned char* __restrict__ b8,
    const unsigned char* __restrict__ u8,
    float* __restrict__ P, float* __restrict__ S) {
  const int g = blockIdx.x * 256 + threadIdx.x;   // 65536 threads
  const int ch = (g & (INNER / 4 - 1)) * 4;
  const int chunk = (g >> 9) & (NCHK - 1);
  const int bb = g >> 14;
  size_t base = ((size_t)bb * SS + (size_t)chunk * CHUNK) * INNER + ch;
  float st0 = 0.f, st1 = 0.f, st2 = 0.f, st3 = 0.f;
  float p0 = 1.f, p1 = 1.f, p2 = 1.f, p3 = 1.f;
  const float bu = ABC8_INV * U_INV;
  for (int t = 0; t < CHUNK; t++) {
    const f32x4 av = up_fp8x4(*(const unsigned*)(a8 + base));
    const f32x4 bv = up_fp8x4(*(const unsigned*)(b8 + base));
    const f32x4 uv = up_fp8x4(*(const unsigned*)(u8 + base));
    const float a0 = av[0] * ABC8_INV, a1 = av[1] * ABC8_INV;
    const float a2 = av[2] * ABC8_INV, a3 = av[3] * ABC8_INV;
    st0 = fmaf(a0, st0, bv[0] * uv[0] * bu); p0 *= a0;
    st1 = fmaf(a1, st1, bv[1] * uv[1] * bu); p1 *= a1;
    st2 = fmaf(a2, st2, bv[2] * uv[2] * bu); p2 *= a2;
    st3 = fmaf(a3, st3, bv[3] * uv[3] * bu); p3 *= a3;
    base += INNER;
  }
  const size_t o = ((size_t)bb * NCHK + chunk) * INNER + ch;
  *(float4*)(P + o) = (float4){p0, p1, p2, p3};
  *(float4*)(S + o) = (float4){st0, st1, st2, st3};
}

__global__ __launch_bounds__(256) void scan_phase2(
    const float* __restrict__ P, const float* __restrict__ S,
    float* __restrict__ Carry) {
  const int g = blockIdx.x * 256 + threadIdx.x;   // 8192 threads
  const int ch = g & (INNER - 1);
  const int bb = g >> 11;
  float carry = 0.f;
  for (int k = 0; k < NCHK; k++) {
    const size_t o = ((size_t)bb * NCHK + k) * INNER + ch;
    Carry[o] = carry;
    carry = fmaf(P[o], carry, S[o]);
  }
}

// Phase 3: redo local scan seeded with carry; y fp8 (xY_SCALE) over u8 in-place.
__global__ __launch_bounds__(256) void scan_phase3(
    const unsigned char* __restrict__ a8, const unsigned char* __restrict__ b8,
    const unsigned char* __restrict__ c8, unsigned char* __restrict__ u8,
    const float* __restrict__ Carry) {
  const int g = blockIdx.x * 256 + threadIdx.x;   // 65536 threads
  const int ch = (g & (INNER / 4 - 1)) * 4;
  const int chunk = (g >> 9) & (NCHK - 1);
  const int bb = g >> 14;
  size_t base = ((size_t)bb * SS + (size_t)chunk * CHUNK) * INNER + ch;
  const size_t o = ((size_t)bb * NCHK + chunk) * INNER + ch;
  const float4 cv = *(const float4*)(Carry + o);
  float st0 = cv.x, st1 = cv.y, st2 = cv.z, st3 = cv.w;
  for (int t = 0; t < CHUNK; t++) {
    const f32x4 av = up_fp8x4(*(const unsigned*)(a8 + base));
    const f32x4 bv = up_fp8x4(*(const unsigned*)(b8 + base));
    const f32x4 ccv = up_fp8x4(*(const unsigned*)(c8 + base));
    const f32x4 uv = up_fp8x4(*(const unsigned*)(u8 + base));
    const float u0 = uv[0] * U_INV, u1 = uv[1] * U_INV;
    const float u2 = uv[2] * U_INV, u3 = uv[3] * U_INV;
    st0 = fmaf(av[0] * ABC8_INV, st0, bv[0] * ABC8_INV * u0);
    st1 = fmaf(av[1] * ABC8_INV, st1, bv[1] * ABC8_INV * u1);
    st2 = fmaf(av[2] * ABC8_INV, st2, bv[2] * ABC8_INV * u2);
    st3 = fmaf(av[3] * ABC8_INV, st3, bv[3] * ABC8_INV * u3);
    const float y0 = fmaf(ccv[0] * ABC8_INV, st0, u0);
    const float y1 = fmaf(ccv[1] * ABC8_INV, st1, u1);
    const float y2 = fmaf(ccv[2] * ABC8_INV, st2, u2);
    const float y3 = fmaf(ccv[3] * ABC8_INV, st3, u3);
    *(unsigned*)(u8 + base) = pk_fp8x4(y0 * Y_SCALE, y1 * Y_SCALE,
                                       y2 * Y_SCALE, y3 * Y_SCALE);
    base += INNER;
  }
}

// ---------------------------------------------------------------------------
extern "C" void kernel_launch(void* const* d_in, const int* in_sizes, int n_in,
                              void* d_out, int out_size, void* d_ws, size_t ws_size,
                              hipStream_t stream) {
  const float* x      = (const float*)d_in[0];
  const float* W_in   = (const float*)d_in[1];
  const float* b_in   = (const float*)d_in[2];
  const float* conv_w = (const float*)d_in[3];
  const float* conv_b = (const float*)d_in[4];
  const float* Wa     = (const float*)d_in[5];
  const float* ba     = (const float*)d_in[6];
  const float* Wb     = (const float*)d_in[7];
  const float* b_b    = (const float*)d_in[8];
  const float* Wc     = (const float*)d_in[9];
  const float* bc     = (const float*)d_in[10];
  const float* Wo     = (const float*)d_in[11];
  const float* bo     = (const float*)d_in[12];
  const float* gamma  = (const float*)d_in[13];
  const float* beta   = (const float*)d_in[14];
  float* out = (float*)d_out;

  const size_t M = (size_t)BB * SS;  // 8192
  char* ws = (char*)d_ws;
  size_t off = 0;
  auto alloc = [&](size_t bytes) {
    char* p = ws + off;
    off += (bytes + 255) & ~(size_t)255;
    return p;
  };
  unsigned char*  Win8   = (unsigned char*)alloc((size_t)4096 * 1024);     // 4 MB
  unsigned char*  Wabc8  = (unsigned char*)alloc((size_t)6144 * 2048);     // 12 MB
  unsigned char*  Wo8    = (unsigned char*)alloc((size_t)1024 * 2048);     // 2 MB
  float*          biasABC = (float*)alloc(6144 * 4);
  unsigned char*  xn8   = (unsigned char*)alloc(M * DM);                   // 8 MB
  unsigned short* proj  = (unsigned short*)alloc(M * 2 * INNER * 2);       // 64 MB
  unsigned char*  u8B   = (unsigned char*)alloc(M * INNER);                // 16 MB
  unsigned char*  abc8  = (unsigned char*)alloc(3 * M * INNER);            // 48 MB
  unsigned char*  aB = abc8;
  unsigned char*  bB = abc8 + M * INNER;
  unsigned char*  cB = abc8 + 2 * M * INNER;
  float* Pbuf  = (float*)alloc((size_t)BB * NCHK * INNER * 4);             // 1 MB
  float* Sbuf  = (float*)alloc((size_t)BB * NCHK * INNER * 4);             // 1 MB
  float* Carry = (float*)alloc((size_t)BB * NCHK * INNER * 4);             // 1 MB

  hipMemcpyAsync(biasABC,        ba,  2048 * 4, hipMemcpyDeviceToDevice, stream);
  hipMemcpyAsync(biasABC + 2048, b_b, 2048 * 4, hipMemcpyDeviceToDevice, stream);
  hipMemcpyAsync(biasABC + 4096, bc,  2048 * 4, hipMemcpyDeviceToDevice, stream);

  const dim3 tb(32, 8);
  transpose_cast_fp8_kernel<<<dim3(128, 32), tb, 0, stream>>>(W_in, Win8, 1024, 4096, WIN_SCALE);
  transpose_cast_fp8_kernel<<<dim3(64, 64), tb, 0, stream>>>(Wa, Wabc8, 2048, 2048, W_SCALE);
  transpose_cast_fp8_kernel<<<dim3(64, 64), tb, 0, stream>>>(Wb, Wabc8 + 2048 * 2048, 2048, 2048, W_SCALE);
  transpose_cast_fp8_kernel<<<dim3(64, 64), tb, 0, stream>>>(Wc, Wabc8 + 2 * 2048 * 2048, 2048, 2048, W_SCALE);
  transpose_cast_fp8_kernel<<<dim3(32, 64), tb, 0, stream>>>(Wo, Wo8, 2048, 1024, WO_SCALE);

  layernorm_kernel<<<M, 256, 0, stream>>>(x, gamma, beta, xn8);

  // proj = xn @ W_in + b_in            [8192 x 4096] MX-fp8 BK=128, grid 512
  gemm_mx<0><<<dim3(512), 512, 0, stream>>>(
      xn8, Win8, b_in, proj, M, 4096, 1024, 16, PROJ_SCALE_INV);

  // u = silu(conv(projected)) * sigmoid(gate)  -> fp8 only
  conv_gate_kernel<<<(M * INNER) / (256 * 8), 256, 0, stream>>>(
      proj, conv_w, conv_b, u8B);

  // a,b,c fused: [8192 x 6144] MX-fp8 BK=128 -> fp8 x16 outputs, grid 768
  gemm_mx<2><<<dim3(768), 512, 0, stream>>>(
      u8B, Wabc8, biasABC, abc8, M, 6144, 2048, 24, ABC_SCALE_INV);

  // chunked scan (y fp8 overwrites u8 in-place)
  scan_phase1<<<256, 256, 0, stream>>>(aB, bB, u8B, Pbuf, Sbuf);
  scan_phase2<<<32, 256, 0, stream>>>(Pbuf, Sbuf, Carry);
  scan_phase3<<<256, 256, 0, stream>>>(aB, bB, cB, u8B, Carry);

  // out = x + y @ Wo + bo              [8192 x 1024] fp32 MX-fp8, grid 256
  gemm_mx_wo<<<dim3(256), 512, 0, stream>>>(
      u8B, Wo8, bo, out, x, M, 1024, 2048, 8);
}

// Round 17
// 339.535 us; speedup vs baseline: 1.0762x; 1.0762x over previous
//
#include <hip/hip_runtime.h>
#include <hip/hip_bf16.h>
#include <cstdint>
#include <cstddef>

#define BB 4
#define SS 2048
#define DM 1024
#define INNER 2048
#define CHUNK 64
#define NCHK (SS / CHUNK)  // 32

typedef __attribute__((ext_vector_type(8))) __bf16 bf16x8;
typedef __attribute__((ext_vector_type(2))) float f32x2;
typedef __attribute__((ext_vector_type(4))) float f32x4;
typedef __attribute__((ext_vector_type(16))) float f32x16;
typedef __attribute__((ext_vector_type(8))) int i32x8;
typedef __attribute__((ext_vector_type(4))) int i32x4;
typedef __attribute__((ext_vector_type(8))) unsigned short ushort8;

#define GPTR(p) ((const __attribute__((address_space(1))) void*)(p))
#define LPTR(p) ((__attribute__((address_space(3))) void*)(p))
#define SB() __builtin_amdgcn_sched_barrier(0)

// Unit E8M0 scales (1.0) -> identical math to non-scaled fp8, 2x MFMA rate.
#define MXMFMA(b, a, c) \
  __builtin_amdgcn_mfma_scale_f32_32x32x64_f8f6f4((b), (a), (c), 0, 0, 0, 0x7f7f7f7f, 0, 0x7f7f7f7f)

// fp8 pre-scales (powers of 2; undone where consumed)
#define XN_SCALE 8.0f
#define WIN_SCALE 32.0f
#define PROJ_SCALE_INV (1.0f / 256.0f)
#define U_SCALE 128.0f
#define U_INV (1.0f / 128.0f)
#define W_SCALE 32.0f
#define ABC_SCALE_INV (1.0f / 4096.0f)
#define ABC8_SCALE 16.0f
#define ABC8_INV (1.0f / 16.0f)
#define Y_SCALE 128.0f
#define WO_SCALE 32.0f
#define WO_SCALE_INV (1.0f / 4096.0f)

__device__ inline float b2f(unsigned short h) {
  union { unsigned u; float f; } v; v.u = ((unsigned)h) << 16; return v.f;
}
__device__ inline unsigned short f2b(float f) {
  unsigned u = __float_as_uint(f);
  u += 0x7fff + ((u >> 16) & 1);   // round-to-nearest-even
  return (unsigned short)(u >> 16);
}
__device__ inline unsigned pack2(float lo, float hi) {
  return (unsigned)f2b(lo) | ((unsigned)f2b(hi) << 16);
}
__device__ inline unsigned pk_fp8x4(float a, float b, float c, float d) {
  unsigned w = 0;
  w = __builtin_amdgcn_cvt_pk_fp8_f32(a, b, (int)w, 0);
  w = __builtin_amdgcn_cvt_pk_fp8_f32(c, d, (int)w, 1);
  return w;
}
// HW fp8->f32: decode dword of 4 e4m3 bytes into f32x4 (2 pk-converts)
__device__ inline f32x4 up_fp8x4(unsigned w) {
  const f32x2 lo = __builtin_amdgcn_cvt_pk_f32_fp8((int)w, false);
  const f32x2 hi = __builtin_amdgcn_cvt_pk_f32_fp8((int)w, true);
  return (f32x4){lo[0], lo[1], hi[0], hi[1]};
}
__device__ inline float sigmoidf_(float x) { return 1.0f / (1.0f + __expf(-x)); }
__device__ inline float tanhf_(float x) { return 2.0f / (1.0f + __expf(-2.0f * x)) - 1.0f; }

// 32-byte MX fragment: two b128 reads at +0 / +256 (k-halves), regs linear in k
__device__ inline i32x8 ld32(const unsigned char* p) {
  i32x4 lo = *(const i32x4*)p;
  i32x4 hi = *(const i32x4*)(p + 256);
  i32x8 r;
  r[0] = lo[0]; r[1] = lo[1]; r[2] = lo[2]; r[3] = lo[3];
  r[4] = hi[0]; r[5] = hi[1]; r[6] = hi[2]; r[7] = hi[3];
  return r;
}

// ---------------------------------------------------------------------------
// Fused prep: 5 fp8 weight transposes + LayerNorm + bias concat, one kernel.
// Block ranges (branch uniform per block):
//   [0,4096)      W_in  1024x4096 -> Win8
//   [4096,8192)   Wa    2048x2048 -> Wabc8+0
//   [8192,12288)  Wb               -> Wabc8+4M
//   [12288,16384) Wc               -> Wabc8+8M
//   [16384,18432) Wo    2048x1024 -> Wo8
//   [18432,26624) LayerNorm row (b-18432)
//   [26624,26648) biasABC concat
// ---------------------------------------------------------------------------
struct PrepArgs {
  const float *W_in, *Wa, *Wb, *Wc, *Wo, *x, *gamma, *beta, *ba, *bb, *bc;
  unsigned char *Win8, *Wabc8, *Wo8, *xn8;
  float *biasABC;
};

__device__ inline void do_transpose_fp8(const float* src, unsigned char* dst,
                                        int R, int C, float scale,
                                        int bx, int by, int tid, float* tile) {
  const int c0 = bx * 32, r0 = by * 32;
  const int tx = tid & 31, ty = tid >> 5;   // (32,8)
  #pragma unroll
  for (int j = ty; j < 32; j += 8)
    tile[j * 33 + tx] = src[(size_t)(r0 + j) * C + c0 + tx];
  __syncthreads();
  #pragma unroll
  for (int j = ty; j < 32; j += 8) {
    const int w = __builtin_amdgcn_cvt_pk_fp8_f32(tile[tx * 33 + j] * scale, 0.f, 0, 0);
    dst[(size_t)(c0 + j) * R + r0 + tx] = (unsigned char)(w & 0xff);
  }
}

__global__ __launch_bounds__(256) void prep_kernel(PrepArgs p) {
  __shared__ float smem[32 * 33];
  const int b = blockIdx.x;
  const int tid = threadIdx.x;
  if (b < 4096) {
    do_transpose_fp8(p.W_in, p.Win8, 1024, 4096, WIN_SCALE, b % 128, b / 128, tid, smem);
  } else if (b < 8192) {
    const int bb_ = b - 4096;
    do_transpose_fp8(p.Wa, p.Wabc8, 2048, 2048, W_SCALE, bb_ % 64, bb_ / 64, tid, smem);
  } else if (b < 12288) {
    const int bb_ = b - 8192;
    do_transpose_fp8(p.Wb, p.Wabc8 + 2048 * 2048, 2048, 2048, W_SCALE, bb_ % 64, bb_ / 64, tid, smem);
  } else if (b < 16384) {
    const int bb_ = b - 12288;
    do_transpose_fp8(p.Wc, p.Wabc8 + 2 * 2048 * 2048, 2048, 2048, W_SCALE, bb_ % 64, bb_ / 64, tid, smem);
  } else if (b < 18432) {
    const int bb_ = b - 16384;
    do_transpose_fp8(p.Wo, p.Wo8, 2048, 1024, WO_SCALE, bb_ % 32, bb_ / 32, tid, smem);
  } else if (b < 26624) {
    // LayerNorm row
    const int row = b - 18432;
    float* red = smem;
    const float4 v = *(const float4*)(p.x + (size_t)row * DM + tid * 4);
    float s = v.x + v.y + v.z + v.w;
    #pragma unroll
    for (int o = 32; o >= 1; o >>= 1) s += __shfl_down(s, o, 64);
    const int wid = tid >> 6, lane = tid & 63;
    if (lane == 0) red[wid] = s;
    __syncthreads();
    const float mu = (red[0] + red[1] + red[2] + red[3]) * (1.f / DM);
    const float d0 = v.x - mu, d1 = v.y - mu, d2 = v.z - mu, d3 = v.w - mu;
    float sq = d0 * d0 + d1 * d1 + d2 * d2 + d3 * d3;
    #pragma unroll
    for (int o = 32; o >= 1; o >>= 1) sq += __shfl_down(sq, o, 64);
    if (lane == 0) red[4 + wid] = sq;
    __syncthreads();
    const float var = (red[4] + red[5] + red[6] + red[7]) * (1.f / DM);
    const float rs = rsqrtf(var + 1e-5f);
    const int c0 = tid * 4;
    const float o0 = (d0 * rs * p.gamma[c0 + 0] + p.beta[c0 + 0]) * XN_SCALE;
    const float o1 = (d1 * rs * p.gamma[c0 + 1] + p.beta[c0 + 1]) * XN_SCALE;
    const float o2 = (d2 * rs * p.gamma[c0 + 2] + p.beta[c0 + 2]) * XN_SCALE;
    const float o3 = (d3 * rs * p.gamma[c0 + 3] + p.beta[c0 + 3]) * XN_SCALE;
    *(unsigned*)(p.xn8 + (size_t)row * DM + c0) = pk_fp8x4(o0, o1, o2, o3);
  } else {
    // bias concat: 24 blocks x 256 = 6144 floats
    const int idx = (b - 26624) * 256 + tid;
    float v;
    if (idx < 2048) v = p.ba[idx];
    else if (idx < 4096) v = p.bb[idx - 2048];
    else v = p.bc[idx - 4096];
    p.biasABC[idx] = v;
  }
}

// ---------------------------------------------------------------------------
// MX-fp8 256x256 GEMM, BK=64 (R14-proven structure, byte-identical).
// LDS layout per 16KB region: addr(r, s16) = (r>>4)*1024 + s*256 + (r&15)*16;
// A @0, B @16384. vmcnt ledger: 2 loads/stage; prologue 4; top +A(t+1)=6,
// vmcnt(2) drains tile t exactly; mid +B(t+1); never drains in loop.
// Swapped operands: lane holds C-row l&31, col clusters 4*(l>>5)+8g+{0..3}.
// OUTMODE 0: bf16 (v = acc*sinv + bias). OUTMODE 2: abc-fused fp8 stores.
// ---------------------------------------------------------------------------
template <int OUTMODE>
__global__ __launch_bounds__(512, 1) void gemm_mx(
    const unsigned char* __restrict__ A, const unsigned char* __restrict__ Bt,
    const float* __restrict__ bias, void* __restrict__ Cout,
    int M, int N, int K, int nbx, float sinv) {
  __shared__ __align__(16) unsigned char lds8[2 * 32768];  // 64 KB
  const int tid = threadIdx.x;
  const int nwg = gridDim.x;
  const int cpx = nwg >> 3;
  const int bid = blockIdx.x;
  const int swz = (bid & 7) * cpx + (bid >> 3);
  const int m0 = (swz / nbx) * 256, n0 = (swz % nbx) * 256;

  const int l = tid & 63, w = tid >> 6;
  const int wr = w >> 2, wc = w & 3;          // 2(M) x 4(N)
  const int NT = K >> 6;                      // K-tiles of 64

  const int lane_a = ((l >> 4) & 1) * 1024 + (l >> 5) * 512 + (l & 15) * 16;
  const int a_base = wr * 8192 + lane_a;              // + mf*2048
  const int b_base = 16384 + wc * 4096 + lane_a;      // + nf*2048

  f32x16 acc[4][2];
  {
    f32x16 z;
    #pragma unroll
    for (int e = 0; e < 16; e++) z[e] = 0.f;
    #pragma unroll
    for (int i = 0; i < 4; i++)
      #pragma unroll
      for (int j = 0; j < 2; j++) acc[i][j] = z;
  }

  const int ru = ((tid >> 6) << 4) | (tid & 15);
  const int su = (tid >> 4) & 3;
  const unsigned char* Af0 = A + (size_t)(m0 + ru) * K + su * 16;
  const unsigned char* Bf0 = Bt + (size_t)(n0 + ru) * K + su * 16;
  const size_t rs128 = (size_t)128 * K;

  auto stageA = [&](int kt) {
    int ktw = kt; if (ktw >= NT) ktw -= NT;
    const int k0 = ktw << 6;
    const int bo = (kt & 1) * 32768;
    __builtin_amdgcn_global_load_lds(GPTR(Af0 + k0), LPTR(&lds8[bo + tid * 16]), 16, 0, 0);
    __builtin_amdgcn_global_load_lds(GPTR(Af0 + rs128 + k0), LPTR(&lds8[bo + (tid + 512) * 16]), 16, 0, 0);
  };
  auto stageB = [&](int kt) {
    int ktw = kt; if (ktw >= NT) ktw -= NT;
    const int k0 = ktw << 6;
    const int bo = (kt & 1) * 32768 + 16384;
    __builtin_amdgcn_global_load_lds(GPTR(Bf0 + k0), LPTR(&lds8[bo + tid * 16]), 16, 0, 0);
    __builtin_amdgcn_global_load_lds(GPTR(Bf0 + rs128 + k0), LPTR(&lds8[bo + (tid + 512) * 16]), 16, 0, 0);
  };

  stageA(0); stageB(0);   // 4 outstanding

  for (int t = 0; t < NT; t++) {
    const int tbo = (t & 1) * 32768;
    i32x8 bf0, bf1, af0, af1, af2, af3;

    stageA(t + 1);
    SB();
    asm volatile("s_waitcnt vmcnt(2)" ::: "memory");
    SB();
    __builtin_amdgcn_s_barrier();
    SB();
    bf0 = ld32(&lds8[tbo + b_base]);
    bf1 = ld32(&lds8[tbo + b_base + 2048]);
    af0 = ld32(&lds8[tbo + a_base]);
    af1 = ld32(&lds8[tbo + a_base + 2048]);
    SB();
    __builtin_amdgcn_s_setprio(1);
    acc[0][0] = MXMFMA(bf0, af0, acc[0][0]);
    acc[0][1] = MXMFMA(bf1, af0, acc[0][1]);
    acc[1][0] = MXMFMA(bf0, af1, acc[1][0]);
    acc[1][1] = MXMFMA(bf1, af1, acc[1][1]);
    __builtin_amdgcn_s_setprio(0);
    SB();
    stageB(t + 1);
    SB();
    af2 = ld32(&lds8[tbo + a_base + 2 * 2048]);
    af3 = ld32(&lds8[tbo + a_base + 3 * 2048]);
    SB();
    __builtin_amdgcn_s_setprio(1);
    acc[2][0] = MXMFMA(bf0, af2, acc[2][0]);
    acc[2][1] = MXMFMA(bf1, af2, acc[2][1]);
    acc[3][0] = MXMFMA(bf0, af3, acc[3][0]);
    acc[3][1] = MXMFMA(bf1, af3, acc[3][1]);
    __builtin_amdgcn_s_setprio(0);
    SB();
    __builtin_amdgcn_s_barrier();
    SB();
  }
  asm volatile("s_waitcnt vmcnt(0)" ::: "memory");

  // epilogue: lane holds C-row l&31, col clusters 4*(l>>5)+8g+{0..3}
  const int rowl = m0 + wr * 128 + (l & 31);
  const int colg = 4 * (l >> 5);
  const int seg = (OUTMODE == 2) ? (n0 >> 11) : 0;
  unsigned char* outseg8 = (unsigned char*)Cout +
      (OUTMODE == 2 ? (size_t)seg * M * 2048 : 0);
  #pragma unroll
  for (int mf = 0; mf < 4; mf++) {
    const int row = rowl + mf * 32;
    #pragma unroll
    for (int nf = 0; nf < 2; nf++) {
      const int nb = n0 + wc * 64 + nf * 32 + colg;
      #pragma unroll
      for (int g = 0; g < 4; g++) {
        const int col = nb + g * 8;
        const float4 bv = *(const float4*)(bias + col);
        float v0 = acc[mf][nf][g * 4 + 0] * sinv + bv.x;
        float v1 = acc[mf][nf][g * 4 + 1] * sinv + bv.y;
        float v2 = acc[mf][nf][g * 4 + 2] * sinv + bv.z;
        float v3 = acc[mf][nf][g * 4 + 3] * sinv + bv.w;
        if (OUTMODE == 2) {
          if (seg == 2) {
            v0 = tanhf_(v0); v1 = tanhf_(v1); v2 = tanhf_(v2); v3 = tanhf_(v3);
          } else {
            v0 = sigmoidf_(v0); v1 = sigmoidf_(v1); v2 = sigmoidf_(v2); v3 = sigmoidf_(v3);
          }
          *(unsigned*)(outseg8 + (size_t)row * 2048 + (col & 2047)) =
              pk_fp8x4(v0 * ABC8_SCALE, v1 * ABC8_SCALE,
                       v2 * ABC8_SCALE, v3 * ABC8_SCALE);
        } else {
          uint2 pk = {pack2(v0, v1), pack2(v2, v3)};
          *(uint2*)((unsigned short*)Cout + (size_t)row * N + col) = pk;
        }
      }
    }
  }
}

// ---------------------------------------------------------------------------
// MX-fp8 256x128 GEMM for Wo (R12-verified, BK=64). fp32 out + bias + resid.
// ---------------------------------------------------------------------------
__global__ __launch_bounds__(512, 1) void gemm_mx_wo(
    const unsigned char* __restrict__ A, const unsigned char* __restrict__ Bt,
    const float* __restrict__ bias, float* __restrict__ Cout,
    const float* __restrict__ resid, int M, int N, int K, int nbx) {
  __shared__ __align__(16) unsigned char lds8[2 * 24576];  // 48 KB
  const int tid = threadIdx.x;
  const int nwg = gridDim.x;
  const int cpx = nwg >> 3;
  const int bid = blockIdx.x;
  const int swz = (bid & 7) * cpx + (bid >> 3);
  const int m0 = (swz / nbx) * 256, n0 = (swz % nbx) * 128;

  const int l = tid & 63, w = tid >> 6;
  const int wr = w >> 1, wc = w & 1;          // 4(M) x 2(N)
  const int NT = K >> 6;

  const int lane_a = ((l >> 4) & 1) * 1024 + (l >> 5) * 512 + (l & 15) * 16;
  const int a_base = wr * 4096 + lane_a;              // + mf*2048
  const int b_base = 16384 + wc * 4096 + lane_a;      // + nf*2048

  f32x16 acc[2][2];
  {
    f32x16 z;
    #pragma unroll
    for (int e = 0; e < 16; e++) z[e] = 0.f;
    acc[0][0] = z; acc[0][1] = z; acc[1][0] = z; acc[1][1] = z;
  }

  const int ru = ((tid >> 6) << 4) | (tid & 15);
  const int su = (tid >> 4) & 3;
  const unsigned char* Af0 = A + (size_t)(m0 + ru) * K + su * 16;
  const unsigned char* Bf0 = Bt + (size_t)(n0 + ru) * K + su * 16;
  const size_t rs128 = (size_t)128 * K;

  auto stageA = [&](int kt) {
    int ktw = kt; if (ktw >= NT) ktw -= NT;
    const int k0 = ktw << 6;
    const int bo = (kt & 1) * 24576;
    __builtin_amdgcn_global_load_lds(GPTR(Af0 + k0), LPTR(&lds8[bo + tid * 16]), 16, 0, 0);
    __builtin_amdgcn_global_load_lds(GPTR(Af0 + rs128 + k0), LPTR(&lds8[bo + (tid + 512) * 16]), 16, 0, 0);
  };
  auto stageB = [&](int kt) {
    int ktw = kt; if (ktw >= NT) ktw -= NT;
    const int k0 = ktw << 6;
    const int bo = (kt & 1) * 24576 + 16384;
    __builtin_amdgcn_global_load_lds(GPTR(Bf0 + k0), LPTR(&lds8[bo + tid * 16]), 16, 0, 0);
  };

  stageA(0); stageB(0);   // 3 outstanding

  for (int t = 0; t < NT; t++) {
    const int tbo = (t & 1) * 24576;
    i32x8 bf0, bf1, af0, af1;

    stageA(t + 1);
    SB();
    asm volatile("s_waitcnt vmcnt(2)" ::: "memory");
    SB();
    __builtin_amdgcn_s_barrier();
    SB();
    bf0 = ld32(&lds8[tbo + b_base]);
    bf1 = ld32(&lds8[tbo + b_base + 2048]);
    af0 = ld32(&lds8[tbo + a_base]);
    SB();
    __builtin_amdgcn_s_setprio(1);
    acc[0][0] = MXMFMA(bf0, af0, acc[0][0]);
    acc[0][1] = MXMFMA(bf1, af0, acc[0][1]);
    __builtin_amdgcn_s_setprio(0);
    SB();
    stageB(t + 1);
    SB();
    af1 = ld32(&lds8[tbo + a_base + 2048]);
    SB();
    __builtin_amdgcn_s_setprio(1);
    acc[1][0] = MXMFMA(bf0, af1, acc[1][0]);
    acc[1][1] = MXMFMA(bf1, af1, acc[1][1]);
    __builtin_amdgcn_s_setprio(0);
    SB();
    __builtin_amdgcn_s_barrier();
    SB();
  }
  asm volatile("s_waitcnt vmcnt(0)" ::: "memory");

  const int rowl = m0 + wr * 64 + (l & 31);
  const int colg = 4 * (l >> 5);
  #pragma unroll
  for (int mf = 0; mf < 2; mf++) {
    const int row = rowl + mf * 32;
    #pragma unroll
    for (int nf = 0; nf < 2; nf++) {
      const int nb = n0 + wc * 64 + nf * 32 + colg;
      #pragma unroll
      for (int g = 0; g < 4; g++) {
        const int col = nb + g * 8;
        const float4 bv = *(const float4*)(bias + col);
        const size_t idx = (size_t)row * N + col;
        const float4 rv = *(const float4*)(resid + idx);
        float4 ov;
        ov.x = acc[mf][nf][g * 4 + 0] * WO_SCALE_INV + bv.x + rv.x;
        ov.y = acc[mf][nf][g * 4 + 1] * WO_SCALE_INV + bv.y + rv.y;
        ov.z = acc[mf][nf][g * 4 + 2] * WO_SCALE_INV + bv.z + rv.z;
        ov.w = acc[mf][nf][g * 4 + 3] * WO_SCALE_INV + bv.w + rv.w;
        *(float4*)(Cout + idx) = ov;
      }
    }
  }
}

// ---------------------------------------------------------------------------
// Causal depthwise conv (K=3) + SiLU + gate. proj bf16 in, u fp8 (x128) out.
// ---------------------------------------------------------------------------
__global__ __launch_bounds__(256) void conv_gate_kernel(
    const unsigned short* __restrict__ proj, const float* __restrict__ conv_w,
    const float* __restrict__ conv_b, unsigned char* __restrict__ u8) {
  const size_t idx = ((size_t)blockIdx.x * 256 + threadIdx.x) * 8;
  const int d = (int)(idx & (INNER - 1));
  const size_t bt = idx >> 11;
  const int t = (int)(bt & (SS - 1));
  const size_t rowbase = bt * (2 * INNER);
  const ushort8 zero = {0, 0, 0, 0, 0, 0, 0, 0};
  ushort8 p0 = *(const ushort8*)(proj + rowbase + d);
  ushort8 p1 = zero, p2 = zero;
  if (t >= 1) p1 = *(const ushort8*)(proj + rowbase - 2 * INNER + d);
  if (t >= 2) p2 = *(const ushort8*)(proj + rowbase - 4 * INNER + d);
  ushort8 g = *(const ushort8*)(proj + rowbase + INNER + d);
  float us[8];
  #pragma unroll
  for (int j = 0; j < 8; j++) {
    const int dj = d + j;
    float sv = conv_b[dj] + conv_w[dj * 3] * b2f(p2[j]) +
               conv_w[dj * 3 + 1] * b2f(p1[j]) + conv_w[dj * 3 + 2] * b2f(p0[j]);
    us[j] = sv * sigmoidf_(sv) * sigmoidf_(b2f(g[j]));
  }
  uint2 pk;
  pk.x = pk_fp8x4(us[0] * U_SCALE, us[1] * U_SCALE, us[2] * U_SCALE, us[3] * U_SCALE);
  pk.y = pk_fp8x4(us[4] * U_SCALE, us[5] * U_SCALE, us[6] * U_SCALE, us[7] * U_SCALE);
  *(uint2*)(u8 + idx) = pk;
}

// ---------------------------------------------------------------------------
// Chunked parallel scan, 3 phases. a,b,c fp8 (x16); u fp8 (x128).
// HW cvt_pk_f32_fp8 decode (2 instrs per 4 elems).
// ---------------------------------------------------------------------------
__global__ __launch_bounds__(256) void scan_phase1(
    const unsigned char* __restrict__ a8, const unsigned char* __restrict__ b8,
    const unsigned char* __restrict__ u8,
    float* __restrict__ P, float* __restrict__ S) {
  const int g = blockIdx.x * 256 + threadIdx.x;   // 65536 threads
  const int ch = (g & (INNER / 4 - 1)) * 4;
  const int chunk = (g >> 9) & (NCHK - 1);
  const int bb = g >> 14;
  size_t base = ((size_t)bb * SS + (size_t)chunk * CHUNK) * INNER + ch;
  float st0 = 0.f, st1 = 0.f, st2 = 0.f, st3 = 0.f;
  float p0 = 1.f, p1 = 1.f, p2 = 1.f, p3 = 1.f;
  const float bu = ABC8_INV * U_INV;
  for (int t = 0; t < CHUNK; t++) {
    const f32x4 av = up_fp8x4(*(const unsigned*)(a8 + base));
    const f32x4 bv = up_fp8x4(*(const unsigned*)(b8 + base));
    const f32x4 uv = up_fp8x4(*(const unsigned*)(u8 + base));
    const float a0 = av[0] * ABC8_INV, a1 = av[1] * ABC8_INV;
    const float a2 = av[2] * ABC8_INV, a3 = av[3] * ABC8_INV;
    st0 = fmaf(a0, st0, bv[0] * uv[0] * bu); p0 *= a0;
    st1 = fmaf(a1, st1, bv[1] * uv[1] * bu); p1 *= a1;
    st2 = fmaf(a2, st2, bv[2] * uv[2] * bu); p2 *= a2;
    st3 = fmaf(a3, st3, bv[3] * uv[3] * bu); p3 *= a3;
    base += INNER;
  }
  const size_t o = ((size_t)bb * NCHK + chunk) * INNER + ch;
  *(float4*)(P + o) = (float4){p0, p1, p2, p3};
  *(float4*)(S + o) = (float4){st0, st1, st2, st3};
}

__global__ __launch_bounds__(256) void scan_phase2(
    const float* __restrict__ P, const float* __restrict__ S,
    float* __restrict__ Carry) {
  const int g = blockIdx.x * 256 + threadIdx.x;   // 8192 threads
  const int ch = g & (INNER - 1);
  const int bb = g >> 11;
  float carry = 0.f;
  for (int k = 0; k < NCHK; k++) {
    const size_t o = ((size_t)bb * NCHK + k) * INNER + ch;
    Carry[o] = carry;
    carry = fmaf(P[o], carry, S[o]);
  }
}

// Phase 3: redo local scan seeded with carry; y fp8 (xY_SCALE) over u8 in-place.
__global__ __launch_bounds__(256) void scan_phase3(
    const unsigned char* __restrict__ a8, const unsigned char* __restrict__ b8,
    const unsigned char* __restrict__ c8, unsigned char* __restrict__ u8,
    const float* __restrict__ Carry) {
  const int g = blockIdx.x * 256 + threadIdx.x;   // 65536 threads
  const int ch = (g & (INNER / 4 - 1)) * 4;
  const int chunk = (g >> 9) & (NCHK - 1);
  const int bb = g >> 14;
  size_t base = ((size_t)bb * SS + (size_t)chunk * CHUNK) * INNER + ch;
  const size_t o = ((size_t)bb * NCHK + chunk) * INNER + ch;
  const float4 cv = *(const float4*)(Carry + o);
  float st0 = cv.x, st1 = cv.y, st2 = cv.z, st3 = cv.w;
  for (int t = 0; t < CHUNK; t++) {
    const f32x4 av = up_fp8x4(*(const unsigned*)(a8 + base));
    const f32x4 bv = up_fp8x4(*(const unsigned*)(b8 + base));
    const f32x4 ccv = up_fp8x4(*(const unsigned*)(c8 + base));
    const f32x4 uv = up_fp8x4(*(const unsigned*)(u8 + base));
    const float u0 = uv[0] * U_INV, u1 = uv[1] * U_INV;
    const float u2 = uv[2] * U_INV, u3 = uv[3] * U_INV;
    st0 = fmaf(av[0] * ABC8_INV, st0, bv[0] * ABC8_INV * u0);
    st1 = fmaf(av[1] * ABC8_INV, st1, bv[1] * ABC8_INV * u1);
    st2 = fmaf(av[2] * ABC8_INV, st2, bv[2] * ABC8_INV * u2);
    st3 = fmaf(av[3] * ABC8_INV, st3, bv[3] * ABC8_INV * u3);
    const float y0 = fmaf(ccv[0] * ABC8_INV, st0, u0);
    const float y1 = fmaf(ccv[1] * ABC8_INV, st1, u1);
    const float y2 = fmaf(ccv[2] * ABC8_INV, st2, u2);
    const float y3 = fmaf(ccv[3] * ABC8_INV, st3, u3);
    *(unsigned*)(u8 + base) = pk_fp8x4(y0 * Y_SCALE, y1 * Y_SCALE,
                                       y2 * Y_SCALE, y3 * Y_SCALE);
    base += INNER;
  }
}

// ---------------------------------------------------------------------------
extern "C" void kernel_launch(void* const* d_in, const int* in_sizes, int n_in,
                              void* d_out, int out_size, void* d_ws, size_t ws_size,
                              hipStream_t stream) {
  const float* x      = (const float*)d_in[0];
  const float* W_in   = (const float*)d_in[1];
  const float* b_in   = (const float*)d_in[2];
  const float* conv_w = (const float*)d_in[3];
  const float* conv_b = (const float*)d_in[4];
  const float* Wa     = (const float*)d_in[5];
  const float* ba     = (const float*)d_in[6];
  const float* Wb     = (const float*)d_in[7];
  const float* b_b    = (const float*)d_in[8];
  const float* Wc     = (const float*)d_in[9];
  const float* bc     = (const float*)d_in[10];
  const float* Wo     = (const float*)d_in[11];
  const float* bo     = (const float*)d_in[12];
  const float* gamma  = (const float*)d_in[13];
  const float* beta   = (const float*)d_in[14];
  float* out = (float*)d_out;

  const size_t M = (size_t)BB * SS;  // 8192
  char* ws = (char*)d_ws;
  size_t off = 0;
  auto alloc = [&](size_t bytes) {
    char* p = ws + off;
    off += (bytes + 255) & ~(size_t)255;
    return p;
  };
  unsigned char*  Win8   = (unsigned char*)alloc((size_t)4096 * 1024);     // 4 MB
  unsigned char*  Wabc8  = (unsigned char*)alloc((size_t)6144 * 2048);     // 12 MB
  unsigned char*  Wo8    = (unsigned char*)alloc((size_t)1024 * 2048);     // 2 MB
  float*          biasABC = (float*)alloc(6144 * 4);
  unsigned char*  xn8   = (unsigned char*)alloc(M * DM);                   // 8 MB
  unsigned short* proj  = (unsigned short*)alloc(M * 2 * INNER * 2);       // 64 MB
  unsigned char*  u8B   = (unsigned char*)alloc(M * INNER);                // 16 MB
  unsigned char*  abc8  = (unsigned char*)alloc(3 * M * INNER);            // 48 MB
  unsigned char*  aB = abc8;
  unsigned char*  bB = abc8 + M * INNER;
  unsigned char*  cB = abc8 + 2 * M * INNER;
  float* Pbuf  = (float*)alloc((size_t)BB * NCHK * INNER * 4);             // 1 MB
  float* Sbuf  = (float*)alloc((size_t)BB * NCHK * INNER * 4);             // 1 MB
  float* Carry = (float*)alloc((size_t)BB * NCHK * INNER * 4);             // 1 MB

  // fused prep: 5 transposes + LN + bias concat
  PrepArgs pa;
  pa.W_in = W_in; pa.Wa = Wa; pa.Wb = Wb; pa.Wc = Wc; pa.Wo = Wo;
  pa.x = x; pa.gamma = gamma; pa.beta = beta;
  pa.ba = ba; pa.bb = b_b; pa.bc = bc;
  pa.Win8 = Win8; pa.Wabc8 = Wabc8; pa.Wo8 = Wo8; pa.xn8 = xn8;
  pa.biasABC = biasABC;
  prep_kernel<<<dim3(26648), 256, 0, stream>>>(pa);

  // proj = xn @ W_in + b_in            [8192 x 4096] MX-fp8, grid 16x32 = 512
  gemm_mx<0><<<dim3(512), 512, 0, stream>>>(
      xn8, Win8, b_in, proj, M, 4096, 1024, 16, PROJ_SCALE_INV);

  // u = silu(conv(projected)) * sigmoid(gate)  -> fp8 only
  conv_gate_kernel<<<(M * INNER) / (256 * 8), 256, 0, stream>>>(
      proj, conv_w, conv_b, u8B);

  // a,b,c fused: [8192 x 6144] MX-fp8 -> fp8 x16 outputs, grid 24x32 = 768
  gemm_mx<2><<<dim3(768), 512, 0, stream>>>(
      u8B, Wabc8, biasABC, abc8, M, 6144, 2048, 24, ABC_SCALE_INV);

  // chunked scan (y fp8 overwrites u8 in-place)
  scan_phase1<<<256, 256, 0, stream>>>(aB, bB, u8B, Pbuf, Sbuf);
  scan_phase2<<<32, 256, 0, stream>>>(Pbuf, Sbuf, Carry);
  scan_phase3<<<256, 256, 0, stream>>>(aB, bB, cB, u8B, Carry);

  // out = x + y @ Wo + bo              [8192 x 1024] fp32 MX-fp8, grid 256
  gemm_mx_wo<<<dim3(256), 512, 0, stream>>>(
      u8B, Wo8, bo, out, x, M, 1024, 2048, 8);
}

// Round 18
// 333.393 us; speedup vs baseline: 1.0960x; 1.0184x over previous
//
#include <hip/hip_runtime.h>
#include <hip/hip_bf16.h>
#include <cstdint>
#include <cstddef>

#define BB 4
#define SS 2048
#define DM 1024
#define INNER 2048
#define CHUNK 64
#define NCHK (SS / CHUNK)  // 32

typedef __attribute__((ext_vector_type(2))) float f32x2;
typedef __attribute__((ext_vector_type(4))) float f32x4;
typedef __attribute__((ext_vector_type(16))) float f32x16;
typedef __attribute__((ext_vector_type(8))) int i32x8;
typedef __attribute__((ext_vector_type(4))) int i32x4;

#define GPTR(p) ((const __attribute__((address_space(1))) void*)(p))
#define LPTR(p) ((__attribute__((address_space(3))) void*)(p))
#define SB() __builtin_amdgcn_sched_barrier(0)

// Unit E8M0 scales (1.0) -> identical math to non-scaled fp8, 2x MFMA rate.
#define MXMFMA(b, a, c) \
  __builtin_amdgcn_mfma_scale_f32_32x32x64_f8f6f4((b), (a), (c), 0, 0, 0, 0x7f7f7f7f, 0, 0x7f7f7f7f)

// fp8 pre-scales (powers of 2; undone where consumed)
#define XN_SCALE 8.0f
#define WIN_SCALE 32.0f
#define PROJ_SCALE_INV (1.0f / 256.0f)
#define PROJ8_SCALE 32.0f
#define PROJ8_INV (1.0f / 32.0f)
#define U_SCALE 128.0f
#define U_INV (1.0f / 128.0f)
#define W_SCALE 32.0f
#define ABC_SCALE_INV (1.0f / 4096.0f)
#define ABC8_SCALE 16.0f
#define ABC8_INV (1.0f / 16.0f)
#define Y_SCALE 128.0f
#define WO_SCALE 32.0f
#define WO_SCALE_INV (1.0f / 4096.0f)

__device__ inline unsigned short f2b(float f) {
  unsigned u = __float_as_uint(f);
  u += 0x7fff + ((u >> 16) & 1);   // round-to-nearest-even
  return (unsigned short)(u >> 16);
}
__device__ inline unsigned pack2(float lo, float hi) {
  return (unsigned)f2b(lo) | ((unsigned)f2b(hi) << 16);
}
__device__ inline unsigned pk_fp8x4(float a, float b, float c, float d) {
  unsigned w = 0;
  w = __builtin_amdgcn_cvt_pk_fp8_f32(a, b, (int)w, 0);
  w = __builtin_amdgcn_cvt_pk_fp8_f32(c, d, (int)w, 1);
  return w;
}
// HW fp8->f32: decode dword of 4 e4m3 bytes into f32x4 (2 pk-converts)
__device__ inline f32x4 up_fp8x4(unsigned w) {
  const f32x2 lo = __builtin_amdgcn_cvt_pk_f32_fp8((int)w, false);
  const f32x2 hi = __builtin_amdgcn_cvt_pk_f32_fp8((int)w, true);
  return (f32x4){lo[0], lo[1], hi[0], hi[1]};
}
__device__ inline float sigmoidf_(float x) { return 1.0f / (1.0f + __expf(-x)); }
__device__ inline float tanhf_(float x) { return 2.0f / (1.0f + __expf(-2.0f * x)) - 1.0f; }

// 32-byte MX fragment: two b128 reads at +0 / +256 (k-halves), regs linear in k
__device__ inline i32x8 ld32(const unsigned char* p) {
  i32x4 lo = *(const i32x4*)p;
  i32x4 hi = *(const i32x4*)(p + 256);
  i32x8 r;
  r[0] = lo[0]; r[1] = lo[1]; r[2] = lo[2]; r[3] = lo[3];
  r[4] = hi[0]; r[5] = hi[1]; r[6] = hi[2]; r[7] = hi[3];
  return r;
}

// ---------------------------------------------------------------------------
// Fused prep: 5 fp8 weight transposes + LayerNorm + bias concat, one kernel.
// ---------------------------------------------------------------------------
struct PrepArgs {
  const float *W_in, *Wa, *Wb, *Wc, *Wo, *x, *gamma, *beta, *ba, *bb, *bc;
  unsigned char *Win8, *Wabc8, *Wo8, *xn8;
  float *biasABC;
};

__device__ inline void do_transpose_fp8(const float* src, unsigned char* dst,
                                        int R, int C, float scale,
                                        int bx, int by, int tid, float* tile) {
  const int c0 = bx * 32, r0 = by * 32;
  const int tx = tid & 31, ty = tid >> 5;   // (32,8)
  #pragma unroll
  for (int j = ty; j < 32; j += 8)
    tile[j * 33 + tx] = src[(size_t)(r0 + j) * C + c0 + tx];
  __syncthreads();
  #pragma unroll
  for (int j = ty; j < 32; j += 8) {
    const int w = __builtin_amdgcn_cvt_pk_fp8_f32(tile[tx * 33 + j] * scale, 0.f, 0, 0);
    dst[(size_t)(c0 + j) * R + r0 + tx] = (unsigned char)(w & 0xff);
  }
}

__global__ __launch_bounds__(256) void prep_kernel(PrepArgs p) {
  __shared__ float smem[32 * 33];
  const int b = blockIdx.x;
  const int tid = threadIdx.x;
  if (b < 4096) {
    do_transpose_fp8(p.W_in, p.Win8, 1024, 4096, WIN_SCALE, b % 128, b / 128, tid, smem);
  } else if (b < 8192) {
    const int bb_ = b - 4096;
    do_transpose_fp8(p.Wa, p.Wabc8, 2048, 2048, W_SCALE, bb_ % 64, bb_ / 64, tid, smem);
  } else if (b < 12288) {
    const int bb_ = b - 8192;
    do_transpose_fp8(p.Wb, p.Wabc8 + 2048 * 2048, 2048, 2048, W_SCALE, bb_ % 64, bb_ / 64, tid, smem);
  } else if (b < 16384) {
    const int bb_ = b - 12288;
    do_transpose_fp8(p.Wc, p.Wabc8 + 2 * 2048 * 2048, 2048, 2048, W_SCALE, bb_ % 64, bb_ / 64, tid, smem);
  } else if (b < 18432) {
    const int bb_ = b - 16384;
    do_transpose_fp8(p.Wo, p.Wo8, 2048, 1024, WO_SCALE, bb_ % 32, bb_ / 32, tid, smem);
  } else if (b < 26624) {
    // LayerNorm row
    const int row = b - 18432;
    float* red = smem;
    const float4 v = *(const float4*)(p.x + (size_t)row * DM + tid * 4);
    float s = v.x + v.y + v.z + v.w;
    #pragma unroll
    for (int o = 32; o >= 1; o >>= 1) s += __shfl_down(s, o, 64);
    const int wid = tid >> 6, lane = tid & 63;
    if (lane == 0) red[wid] = s;
    __syncthreads();
    const float mu = (red[0] + red[1] + red[2] + red[3]) * (1.f / DM);
    const float d0 = v.x - mu, d1 = v.y - mu, d2 = v.z - mu, d3 = v.w - mu;
    float sq = d0 * d0 + d1 * d1 + d2 * d2 + d3 * d3;
    #pragma unroll
    for (int o = 32; o >= 1; o >>= 1) sq += __shfl_down(sq, o, 64);
    if (lane == 0) red[4 + wid] = sq;
    __syncthreads();
    const float var = (red[4] + red[5] + red[6] + red[7]) * (1.f / DM);
    const float rs = rsqrtf(var + 1e-5f);
    const int c0 = tid * 4;
    const float o0 = (d0 * rs * p.gamma[c0 + 0] + p.beta[c0 + 0]) * XN_SCALE;
    const float o1 = (d1 * rs * p.gamma[c0 + 1] + p.beta[c0 + 1]) * XN_SCALE;
    const float o2 = (d2 * rs * p.gamma[c0 + 2] + p.beta[c0 + 2]) * XN_SCALE;
    const float o3 = (d3 * rs * p.gamma[c0 + 3] + p.beta[c0 + 3]) * XN_SCALE;
    *(unsigned*)(p.xn8 + (size_t)row * DM + c0) = pk_fp8x4(o0, o1, o2, o3);
  } else {
    const int idx = (b - 26624) * 256 + tid;
    float v;
    if (idx < 2048) v = p.ba[idx];
    else if (idx < 4096) v = p.bb[idx - 2048];
    else v = p.bc[idx - 4096];
    p.biasABC[idx] = v;
  }
}

// ---------------------------------------------------------------------------
// MX-fp8 256x256 GEMM, BK=64 (R14-proven structure).
// OUTMODE 0: fp8 x PROJ8_SCALE store (proj). OUTMODE 2: abc-fused fp8 stores.
// ---------------------------------------------------------------------------
template <int OUTMODE>
__global__ __launch_bounds__(512, 1) void gemm_mx(
    const unsigned char* __restrict__ A, const unsigned char* __restrict__ Bt,
    const float* __restrict__ bias, void* __restrict__ Cout,
    int M, int N, int K, int nbx, float sinv) {
  __shared__ __align__(16) unsigned char lds8[2 * 32768];  // 64 KB
  const int tid = threadIdx.x;
  const int nwg = gridDim.x;
  const int cpx = nwg >> 3;
  const int bid = blockIdx.x;
  const int swz = (bid & 7) * cpx + (bid >> 3);
  const int m0 = (swz / nbx) * 256, n0 = (swz % nbx) * 256;

  const int l = tid & 63, w = tid >> 6;
  const int wr = w >> 2, wc = w & 3;          // 2(M) x 4(N)
  const int NT = K >> 6;                      // K-tiles of 64

  const int lane_a = ((l >> 4) & 1) * 1024 + (l >> 5) * 512 + (l & 15) * 16;
  const int a_base = wr * 8192 + lane_a;              // + mf*2048
  const int b_base = 16384 + wc * 4096 + lane_a;      // + nf*2048

  f32x16 acc[4][2];
  {
    f32x16 z;
    #pragma unroll
    for (int e = 0; e < 16; e++) z[e] = 0.f;
    #pragma unroll
    for (int i = 0; i < 4; i++)
      #pragma unroll
      for (int j = 0; j < 2; j++) acc[i][j] = z;
  }

  const int ru = ((tid >> 6) << 4) | (tid & 15);
  const int su = (tid >> 4) & 3;
  const unsigned char* Af0 = A + (size_t)(m0 + ru) * K + su * 16;
  const unsigned char* Bf0 = Bt + (size_t)(n0 + ru) * K + su * 16;
  const size_t rs128 = (size_t)128 * K;

  auto stageA = [&](int kt) {
    int ktw = kt; if (ktw >= NT) ktw -= NT;
    const int k0 = ktw << 6;
    const int bo = (kt & 1) * 32768;
    __builtin_amdgcn_global_load_lds(GPTR(Af0 + k0), LPTR(&lds8[bo + tid * 16]), 16, 0, 0);
    __builtin_amdgcn_global_load_lds(GPTR(Af0 + rs128 + k0), LPTR(&lds8[bo + (tid + 512) * 16]), 16, 0, 0);
  };
  auto stageB = [&](int kt) {
    int ktw = kt; if (ktw >= NT) ktw -= NT;
    const int k0 = ktw << 6;
    const int bo = (kt & 1) * 32768 + 16384;
    __builtin_amdgcn_global_load_lds(GPTR(Bf0 + k0), LPTR(&lds8[bo + tid * 16]), 16, 0, 0);
    __builtin_amdgcn_global_load_lds(GPTR(Bf0 + rs128 + k0), LPTR(&lds8[bo + (tid + 512) * 16]), 16, 0, 0);
  };

  stageA(0); stageB(0);   // 4 outstanding

  for (int t = 0; t < NT; t++) {
    const int tbo = (t & 1) * 32768;
    i32x8 bf0, bf1, af0, af1, af2, af3;

    stageA(t + 1);
    SB();
    asm volatile("s_waitcnt vmcnt(2)" ::: "memory");
    SB();
    __builtin_amdgcn_s_barrier();
    SB();
    bf0 = ld32(&lds8[tbo + b_base]);
    bf1 = ld32(&lds8[tbo + b_base + 2048]);
    af0 = ld32(&lds8[tbo + a_base]);
    af1 = ld32(&lds8[tbo + a_base + 2048]);
    SB();
    __builtin_amdgcn_s_setprio(1);
    acc[0][0] = MXMFMA(bf0, af0, acc[0][0]);
    acc[0][1] = MXMFMA(bf1, af0, acc[0][1]);
    acc[1][0] = MXMFMA(bf0, af1, acc[1][0]);
    acc[1][1] = MXMFMA(bf1, af1, acc[1][1]);
    __builtin_amdgcn_s_setprio(0);
    SB();
    stageB(t + 1);
    SB();
    af2 = ld32(&lds8[tbo + a_base + 2 * 2048]);
    af3 = ld32(&lds8[tbo + a_base + 3 * 2048]);
    SB();
    __builtin_amdgcn_s_setprio(1);
    acc[2][0] = MXMFMA(bf0, af2, acc[2][0]);
    acc[2][1] = MXMFMA(bf1, af2, acc[2][1]);
    acc[3][0] = MXMFMA(bf0, af3, acc[3][0]);
    acc[3][1] = MXMFMA(bf1, af3, acc[3][1]);
    __builtin_amdgcn_s_setprio(0);
    SB();
    __builtin_amdgcn_s_barrier();
    SB();
  }
  asm volatile("s_waitcnt vmcnt(0)" ::: "memory");

  // epilogue: lane holds C-row l&31, col clusters 4*(l>>5)+8g+{0..3}
  const int rowl = m0 + wr * 128 + (l & 31);
  const int colg = 4 * (l >> 5);
  const int seg = (OUTMODE == 2) ? (n0 >> 11) : 0;
  unsigned char* outseg8 = (unsigned char*)Cout +
      (OUTMODE == 2 ? (size_t)seg * M * 2048 : 0);
  #pragma unroll
  for (int mf = 0; mf < 4; mf++) {
    const int row = rowl + mf * 32;
    #pragma unroll
    for (int nf = 0; nf < 2; nf++) {
      const int nb = n0 + wc * 64 + nf * 32 + colg;
      #pragma unroll
      for (int g = 0; g < 4; g++) {
        const int col = nb + g * 8;
        const float4 bv = *(const float4*)(bias + col);
        float v0 = acc[mf][nf][g * 4 + 0] * sinv + bv.x;
        float v1 = acc[mf][nf][g * 4 + 1] * sinv + bv.y;
        float v2 = acc[mf][nf][g * 4 + 2] * sinv + bv.z;
        float v3 = acc[mf][nf][g * 4 + 3] * sinv + bv.w;
        if (OUTMODE == 2) {
          if (seg == 2) {
            v0 = tanhf_(v0); v1 = tanhf_(v1); v2 = tanhf_(v2); v3 = tanhf_(v3);
          } else {
            v0 = sigmoidf_(v0); v1 = sigmoidf_(v1); v2 = sigmoidf_(v2); v3 = sigmoidf_(v3);
          }
          *(unsigned*)(outseg8 + (size_t)row * 2048 + (col & 2047)) =
              pk_fp8x4(v0 * ABC8_SCALE, v1 * ABC8_SCALE,
                       v2 * ABC8_SCALE, v3 * ABC8_SCALE);
        } else {
          // proj: fp8 x PROJ8_SCALE
          *(unsigned*)((unsigned char*)Cout + (size_t)row * N + col) =
              pk_fp8x4(v0 * PROJ8_SCALE, v1 * PROJ8_SCALE,
                       v2 * PROJ8_SCALE, v3 * PROJ8_SCALE);
        }
      }
    }
  }
}

// ---------------------------------------------------------------------------
// MX-fp8 256x128 GEMM for Wo (R12-verified, BK=64). fp32 out + bias + resid.
// ---------------------------------------------------------------------------
__global__ __launch_bounds__(512, 1) void gemm_mx_wo(
    const unsigned char* __restrict__ A, const unsigned char* __restrict__ Bt,
    const float* __restrict__ bias, float* __restrict__ Cout,
    const float* __restrict__ resid, int M, int N, int K, int nbx) {
  __shared__ __align__(16) unsigned char lds8[2 * 24576];  // 48 KB
  const int tid = threadIdx.x;
  const int nwg = gridDim.x;
  const int cpx = nwg >> 3;
  const int bid = blockIdx.x;
  const int swz = (bid & 7) * cpx + (bid >> 3);
  const int m0 = (swz / nbx) * 256, n0 = (swz % nbx) * 128;

  const int l = tid & 63, w = tid >> 6;
  const int wr = w >> 1, wc = w & 1;          // 4(M) x 2(N)
  const int NT = K >> 6;

  const int lane_a = ((l >> 4) & 1) * 1024 + (l >> 5) * 512 + (l & 15) * 16;
  const int a_base = wr * 4096 + lane_a;              // + mf*2048
  const int b_base = 16384 + wc * 4096 + lane_a;      // + nf*2048

  f32x16 acc[2][2];
  {
    f32x16 z;
    #pragma unroll
    for (int e = 0; e < 16; e++) z[e] = 0.f;
    acc[0][0] = z; acc[0][1] = z; acc[1][0] = z; acc[1][1] = z;
  }

  const int ru = ((tid >> 6) << 4) | (tid & 15);
  const int su = (tid >> 4) & 3;
  const unsigned char* Af0 = A + (size_t)(m0 + ru) * K + su * 16;
  const unsigned char* Bf0 = Bt + (size_t)(n0 + ru) * K + su * 16;
  const size_t rs128 = (size_t)128 * K;

  auto stageA = [&](int kt) {
    int ktw = kt; if (ktw >= NT) ktw -= NT;
    const int k0 = ktw << 6;
    const int bo = (kt & 1) * 24576;
    __builtin_amdgcn_global_load_lds(GPTR(Af0 + k0), LPTR(&lds8[bo + tid * 16]), 16, 0, 0);
    __builtin_amdgcn_global_load_lds(GPTR(Af0 + rs128 + k0), LPTR(&lds8[bo + (tid + 512) * 16]), 16, 0, 0);
  };
  auto stageB = [&](int kt) {
    int ktw = kt; if (ktw >= NT) ktw -= NT;
    const int k0 = ktw << 6;
    const int bo = (kt & 1) * 24576 + 16384;
    __builtin_amdgcn_global_load_lds(GPTR(Bf0 + k0), LPTR(&lds8[bo + tid * 16]), 16, 0, 0);
  };

  stageA(0); stageB(0);   // 3 outstanding

  for (int t = 0; t < NT; t++) {
    const int tbo = (t & 1) * 24576;
    i32x8 bf0, bf1, af0, af1;

    stageA(t + 1);
    SB();
    asm volatile("s_waitcnt vmcnt(2)" ::: "memory");
    SB();
    __builtin_amdgcn_s_barrier();
    SB();
    bf0 = ld32(&lds8[tbo + b_base]);
    bf1 = ld32(&lds8[tbo + b_base + 2048]);
    af0 = ld32(&lds8[tbo + a_base]);
    SB();
    __builtin_amdgcn_s_setprio(1);
    acc[0][0] = MXMFMA(bf0, af0, acc[0][0]);
    acc[0][1] = MXMFMA(bf1, af0, acc[0][1]);
    __builtin_amdgcn_s_setprio(0);
    SB();
    stageB(t + 1);
    SB();
    af1 = ld32(&lds8[tbo + a_base + 2048]);
    SB();
    __builtin_amdgcn_s_setprio(1);
    acc[1][0] = MXMFMA(bf0, af1, acc[1][0]);
    acc[1][1] = MXMFMA(bf1, af1, acc[1][1]);
    __builtin_amdgcn_s_setprio(0);
    SB();
    __builtin_amdgcn_s_barrier();
    SB();
  }
  asm volatile("s_waitcnt vmcnt(0)" ::: "memory");

  const int rowl = m0 + wr * 64 + (l & 31);
  const int colg = 4 * (l >> 5);
  #pragma unroll
  for (int mf = 0; mf < 2; mf++) {
    const int row = rowl + mf * 32;
    #pragma unroll
    for (int nf = 0; nf < 2; nf++) {
      const int nb = n0 + wc * 64 + nf * 32 + colg;
      #pragma unroll
      for (int g = 0; g < 4; g++) {
        const int col = nb + g * 8;
        const float4 bv = *(const float4*)(bias + col);
        const size_t idx = (size_t)row * N + col;
        const float4 rv = *(const float4*)(resid + idx);
        float4 ov;
        ov.x = acc[mf][nf][g * 4 + 0] * WO_SCALE_INV + bv.x + rv.x;
        ov.y = acc[mf][nf][g * 4 + 1] * WO_SCALE_INV + bv.y + rv.y;
        ov.z = acc[mf][nf][g * 4 + 2] * WO_SCALE_INV + bv.z + rv.z;
        ov.w = acc[mf][nf][g * 4 + 3] * WO_SCALE_INV + bv.w + rv.w;
        *(float4*)(Cout + idx) = ov;
      }
    }
  }
}

// ---------------------------------------------------------------------------
// Causal depthwise conv (K=3) + SiLU + gate. proj fp8 (x32) in, u fp8 (x128) out.
// ---------------------------------------------------------------------------
__global__ __launch_bounds__(256) void conv_gate_kernel(
    const unsigned char* __restrict__ proj8, const float* __restrict__ conv_w,
    const float* __restrict__ conv_b, unsigned char* __restrict__ u8) {
  const size_t idx = ((size_t)blockIdx.x * 256 + threadIdx.x) * 8;
  const int d = (int)(idx & (INNER - 1));
  const size_t bt = idx >> 11;
  const int t = (int)(bt & (SS - 1));
  const size_t rowbase = bt * (2 * INNER);
  uint2 w0 = *(const uint2*)(proj8 + rowbase + d);
  uint2 w1 = {0u, 0u}, w2 = {0u, 0u};
  if (t >= 1) w1 = *(const uint2*)(proj8 + rowbase - 2 * INNER + d);
  if (t >= 2) w2 = *(const uint2*)(proj8 + rowbase - 4 * INNER + d);
  uint2 wg = *(const uint2*)(proj8 + rowbase + INNER + d);
  float p0[8], p1[8], p2[8], gg[8];
  {
    const f32x4 a0 = up_fp8x4(w0.x), a1 = up_fp8x4(w0.y);
    const f32x4 b0 = up_fp8x4(w1.x), b1 = up_fp8x4(w1.y);
    const f32x4 c0 = up_fp8x4(w2.x), c1 = up_fp8x4(w2.y);
    const f32x4 g0 = up_fp8x4(wg.x), g1 = up_fp8x4(wg.y);
    #pragma unroll
    for (int j = 0; j < 4; j++) {
      p0[j] = a0[j] * PROJ8_INV; p0[4 + j] = a1[j] * PROJ8_INV;
      p1[j] = b0[j] * PROJ8_INV; p1[4 + j] = b1[j] * PROJ8_INV;
      p2[j] = c0[j] * PROJ8_INV; p2[4 + j] = c1[j] * PROJ8_INV;
      gg[j] = g0[j] * PROJ8_INV; gg[4 + j] = g1[j] * PROJ8_INV;
    }
  }
  float us[8];
  #pragma unroll
  for (int j = 0; j < 8; j++) {
    const int dj = d + j;
    float sv = conv_b[dj] + conv_w[dj * 3] * p2[j] +
               conv_w[dj * 3 + 1] * p1[j] + conv_w[dj * 3 + 2] * p0[j];
    us[j] = sv * sigmoidf_(sv) * sigmoidf_(gg[j]);
  }
  uint2 pk;
  pk.x = pk_fp8x4(us[0] * U_SCALE, us[1] * U_SCALE, us[2] * U_SCALE, us[3] * U_SCALE);
  pk.y = pk_fp8x4(us[4] * U_SCALE, us[5] * U_SCALE, us[6] * U_SCALE, us[7] * U_SCALE);
  *(uint2*)(u8 + idx) = pk;
}

// ---------------------------------------------------------------------------
// Chunked parallel scan, 3 phases. a,b,c fp8 (x16); u fp8 (x128).
// ---------------------------------------------------------------------------
__global__ __launch_bounds__(256) void scan_phase1(
    const unsigned char* __restrict__ a8, const unsigned char* __restrict__ b8,
    const unsigned char* __restrict__ u8,
    float* __restrict__ P, float* __restrict__ S) {
  const int g = blockIdx.x * 256 + threadIdx.x;   // 65536 threads
  const int ch = (g & (INNER / 4 - 1)) * 4;
  const int chunk = (g >> 9) & (NCHK - 1);
  const int bb = g >> 14;
  size_t base = ((size_t)bb * SS + (size_t)chunk * CHUNK) * INNER + ch;
  float st0 = 0.f, st1 = 0.f, st2 = 0.f, st3 = 0.f;
  float p0 = 1.f, p1 = 1.f, p2 = 1.f, p3 = 1.f;
  const float bu = ABC8_INV * U_INV;
  for (int t = 0; t < CHUNK; t++) {
    const f32x4 av = up_fp8x4(*(const unsigned*)(a8 + base));
    const f32x4 bv = up_fp8x4(*(const unsigned*)(b8 + base));
    const f32x4 uv = up_fp8x4(*(const unsigned*)(u8 + base));
    const float a0 = av[0] * ABC8_INV, a1 = av[1] * ABC8_INV;
    const float a2 = av[2] * ABC8_INV, a3 = av[3] * ABC8_INV;
    st0 = fmaf(a0, st0, bv[0] * uv[0] * bu); p0 *= a0;
    st1 = fmaf(a1, st1, bv[1] * uv[1] * bu); p1 *= a1;
    st2 = fmaf(a2, st2, bv[2] * uv[2] * bu); p2 *= a2;
    st3 = fmaf(a3, st3, bv[3] * uv[3] * bu); p3 *= a3;
    base += INNER;
  }
  const size_t o = ((size_t)bb * NCHK + chunk) * INNER + ch;
  *(float4*)(P + o) = (float4){p0, p1, p2, p3};
  *(float4*)(S + o) = (float4){st0, st1, st2, st3};
}

__global__ __launch_bounds__(256) void scan_phase2(
    const float* __restrict__ P, const float* __restrict__ S,
    float* __restrict__ Carry) {
  const int g = blockIdx.x * 256 + threadIdx.x;   // 8192 threads
  const int ch = g & (INNER - 1);
  const int bb = g >> 11;
  float carry = 0.f;
  for (int k = 0; k < NCHK; k++) {
    const size_t o = ((size_t)bb * NCHK + k) * INNER + ch;
    Carry[o] = carry;
    carry = fmaf(P[o], carry, S[o]);
  }
}

// Phase 3: redo local scan seeded with carry; y fp8 (xY_SCALE) over u8 in-place.
__global__ __launch_bounds__(256) void scan_phase3(
    const unsigned char* __restrict__ a8, const unsigned char* __restrict__ b8,
    const unsigned char* __restrict__ c8, unsigned char* __restrict__ u8,
    const float* __restrict__ Carry) {
  const int g = blockIdx.x * 256 + threadIdx.x;   // 65536 threads
  const int ch = (g & (INNER / 4 - 1)) * 4;
  const int chunk = (g >> 9) & (NCHK - 1);
  const int bb = g >> 14;
  size_t base = ((size_t)bb * SS + (size_t)chunk * CHUNK) * INNER + ch;
  const size_t o = ((size_t)bb * NCHK + chunk) * INNER + ch;
  const float4 cv = *(const float4*)(Carry + o);
  float st0 = cv.x, st1 = cv.y, st2 = cv.z, st3 = cv.w;
  for (int t = 0; t < CHUNK; t++) {
    const f32x4 av = up_fp8x4(*(const unsigned*)(a8 + base));
    const f32x4 bv = up_fp8x4(*(const unsigned*)(b8 + base));
    const f32x4 ccv = up_fp8x4(*(const unsigned*)(c8 + base));
    const f32x4 uv = up_fp8x4(*(const unsigned*)(u8 + base));
    const float u0 = uv[0] * U_INV, u1 = uv[1] * U_INV;
    const float u2 = uv[2] * U_INV, u3 = uv[3] * U_INV;
    st0 = fmaf(av[0] * ABC8_INV, st0, bv[0] * ABC8_INV * u0);
    st1 = fmaf(av[1] * ABC8_INV, st1, bv[1] * ABC8_INV * u1);
    st2 = fmaf(av[2] * ABC8_INV, st2, bv[2] * ABC8_INV * u2);
    st3 = fmaf(av[3] * ABC8_INV, st3, bv[3] * ABC8_INV * u3);
    const float y0 = fmaf(ccv[0] * ABC8_INV, st0, u0);
    const float y1 = fmaf(ccv[1] * ABC8_INV, st1, u1);
    const float y2 = fmaf(ccv[2] * ABC8_INV, st2, u2);
    const float y3 = fmaf(ccv[3] * ABC8_INV, st3, u3);
    *(unsigned*)(u8 + base) = pk_fp8x4(y0 * Y_SCALE, y1 * Y_SCALE,
                                       y2 * Y_SCALE, y3 * Y_SCALE);
    base += INNER;
  }
}

// ---------------------------------------------------------------------------
extern "C" void kernel_launch(void* const* d_in, const int* in_sizes, int n_in,
                              void* d_out, int out_size, void* d_ws, size_t ws_size,
                              hipStream_t stream) {
  const float* x      = (const float*)d_in[0];
  const float* W_in   = (const float*)d_in[1];
  const float* b_in   = (const float*)d_in[2];
  const float* conv_w = (const float*)d_in[3];
  const float* conv_b = (const float*)d_in[4];
  const float* Wa     = (const float*)d_in[5];
  const float* ba     = (const float*)d_in[6];
  const float* Wb     = (const float*)d_in[7];
  const float* b_b    = (const float*)d_in[8];
  const float* Wc     = (const float*)d_in[9];
  const float* bc     = (const float*)d_in[10];
  const float* Wo     = (const float*)d_in[11];
  const float* bo     = (const float*)d_in[12];
  const float* gamma  = (const float*)d_in[13];
  const float* beta   = (const float*)d_in[14];
  float* out = (float*)d_out;

  const size_t M = (size_t)BB * SS;  // 8192
  char* ws = (char*)d_ws;
  size_t off = 0;
  auto alloc = [&](size_t bytes) {
    char* p = ws + off;
    off += (bytes + 255) & ~(size_t)255;
    return p;
  };
  unsigned char*  Win8   = (unsigned char*)alloc((size_t)4096 * 1024);     // 4 MB
  unsigned char*  Wabc8  = (unsigned char*)alloc((size_t)6144 * 2048);     // 12 MB
  unsigned char*  Wo8    = (unsigned char*)alloc((size_t)1024 * 2048);     // 2 MB
  float*          biasABC = (float*)alloc(6144 * 4);
  unsigned char*  xn8   = (unsigned char*)alloc(M * DM);                   // 8 MB
  unsigned char*  proj8 = (unsigned char*)alloc(M * 2 * INNER);            // 32 MB
  unsigned char*  u8B   = (unsigned char*)alloc(M * INNER);                // 16 MB
  unsigned char*  abc8  = (unsigned char*)alloc(3 * M * INNER);            // 48 MB
  unsigned char*  aB = abc8;
  unsigned char*  bB = abc8 + M * INNER;
  unsigned char*  cB = abc8 + 2 * M * INNER;
  float* Pbuf  = (float*)alloc((size_t)BB * NCHK * INNER * 4);             // 1 MB
  float* Sbuf  = (float*)alloc((size_t)BB * NCHK * INNER * 4);             // 1 MB
  float* Carry = (float*)alloc((size_t)BB * NCHK * INNER * 4);             // 1 MB

  // fused prep: 5 transposes + LN + bias concat
  PrepArgs pa;
  pa.W_in = W_in; pa.Wa = Wa; pa.Wb = Wb; pa.Wc = Wc; pa.Wo = Wo;
  pa.x = x; pa.gamma = gamma; pa.beta = beta;
  pa.ba = ba; pa.bb = b_b; pa.bc = bc;
  pa.Win8 = Win8; pa.Wabc8 = Wabc8; pa.Wo8 = Wo8; pa.xn8 = xn8;
  pa.biasABC = biasABC;
  prep_kernel<<<dim3(26648), 256, 0, stream>>>(pa);

  // proj = xn @ W_in + b_in            [8192 x 4096] MX-fp8 -> fp8 x32
  gemm_mx<0><<<dim3(512), 512, 0, stream>>>(
      xn8, Win8, b_in, proj8, M, 4096, 1024, 16, PROJ_SCALE_INV);

  // u = silu(conv(projected)) * sigmoid(gate)  -> fp8
  conv_gate_kernel<<<(M * INNER) / (256 * 8), 256, 0, stream>>>(
      proj8, conv_w, conv_b, u8B);

  // a,b,c fused: [8192 x 6144] MX-fp8 -> fp8 x16 outputs, grid 24x32 = 768
  gemm_mx<2><<<dim3(768), 512, 0, stream>>>(
      u8B, Wabc8, biasABC, abc8, M, 6144, 2048, 24, ABC_SCALE_INV);

  // chunked scan (y fp8 overwrites u8 in-place)
  scan_phase1<<<256, 256, 0, stream>>>(aB, bB, u8B, Pbuf, Sbuf);
  scan_phase2<<<32, 256, 0, stream>>>(Pbuf, Sbuf, Carry);
  scan_phase3<<<256, 256, 0, stream>>>(aB, bB, cB, u8B, Carry);

  // out = x + y @ Wo + bo              [8192 x 1024] fp32 MX-fp8, grid 256
  gemm_mx_wo<<<dim3(256), 512, 0, stream>>>(
      u8B, Wo8, bo, out, x, M, 1024, 2048, 8);
}